// Round 4
// baseline (6888.927 us; speedup 1.0000x reference)
//
#include <hip/hip_runtime.h>

#define HIDDEN 128
#define N_NODES 10000
#define E_LOCAL 320000
#define E_GLOBAL 640000

// ---------------- GEMM: out[N,M] = A[N,K] @ W[K,M] (+bias) (+=) ----------------
// 64x64 tile, 256 threads, 4x4 microtile per thread.
template<int K, bool ACCUM>
__global__ __launch_bounds__(256) void gemm_bias(const float* __restrict__ A,
    const float* __restrict__ W, const float* __restrict__ bias,
    float* __restrict__ out, int N, int M) {
  __shared__ float As[16][64];   // As[k][row]
  __shared__ float Ws[16][64];   // Ws[k][col]
  const int tid = threadIdx.x;
  const int tx = tid & 15;       // col group
  const int ty = tid >> 4;       // row group
  const int row0 = blockIdx.y * 64;
  const int col0 = blockIdx.x * 64;
  const int lr = tid >> 2;       // A row within tile (0..63)
  const int lk = tid & 3;        // A float4 index within 16-k chunk
  const int wr = tid >> 4;       // W k-row (0..15)
  const int wc = tid & 15;       // W float4 col
  float acc[4][4] = {};
  for (int k0 = 0; k0 < K; k0 += 16) {
    int gr = row0 + lr; if (gr >= N) gr = N - 1;   // clamp (stores are guarded)
    float4 av = *reinterpret_cast<const float4*>(&A[(long)gr * K + k0 + lk * 4]);
    float4 wv = *reinterpret_cast<const float4*>(&W[(long)(k0 + wr) * M + col0 + wc * 4]);
    __syncthreads();
    As[lk * 4 + 0][lr] = av.x;
    As[lk * 4 + 1][lr] = av.y;
    As[lk * 4 + 2][lr] = av.z;
    As[lk * 4 + 3][lr] = av.w;
    *reinterpret_cast<float4*>(&Ws[wr][wc * 4]) = wv;
    __syncthreads();
    #pragma unroll
    for (int k = 0; k < 16; ++k) {
      float4 a4 = *reinterpret_cast<const float4*>(&As[k][ty * 4]);
      float4 b4 = *reinterpret_cast<const float4*>(&Ws[k][tx * 4]);
      float aa[4] = {a4.x, a4.y, a4.z, a4.w};
      float bb[4] = {b4.x, b4.y, b4.z, b4.w};
      #pragma unroll
      for (int i = 0; i < 4; ++i)
        #pragma unroll
        for (int j = 0; j < 4; ++j)
          acc[i][j] = fmaf(aa[i], bb[j], acc[i][j]);
    }
  }
  #pragma unroll
  for (int i = 0; i < 4; ++i) {
    int r = row0 + ty * 4 + i;
    if (r >= N) continue;
    #pragma unroll
    for (int j = 0; j < 4; ++j) {
      int c = col0 + tx * 4 + j;
      float v = acc[i][j];
      if (bias) v += bias[c];
      if (ACCUM) out[(long)r * M + c] += v;
      else       out[(long)r * M + c] = v;
    }
  }
}

// ---------------- Edge pass: one wave per message ----------------
// acc[d] += exp(logit) * xl[s];  denom[d,h] += exp(logit)
template<int H>
__global__ __launch_bounds__(256) void edge_pass(const float* __restrict__ xl,
    const float* __restrict__ xr, const float* __restrict__ att,
    const int* __restrict__ srcs, const int* __restrict__ dsts,
    int E, float* __restrict__ acc, float* __restrict__ denom) {
  constexpr int TC = H * 128;     // total channels
  constexpr int PER = TC / 64;    // floats per lane (8 for H=4, 4 for H=2)
  constexpr int NV = PER / 4;     // float4s per lane
  constexpr int GRP = 64 / H;     // lanes per head
  const int lane = threadIdx.x & 63;
  const int wid = (blockIdx.x * blockDim.x + threadIdx.x) >> 6;
  const int nw = (gridDim.x * blockDim.x) >> 6;
  const int head = lane / GRP;
  const int base = lane * PER;
  float attv[PER];
  #pragma unroll
  for (int p = 0; p < PER; ++p) attv[p] = att[base + p];
  const int M = E + N_NODES;      // edges + self loops
  for (int m = wid; m < M; m += nw) {
    int s, d;
    if (m < E) { s = srcs[m]; d = dsts[m]; } else { s = m - E; d = s; }
    float xs[PER];
    float partial = 0.f;
    #pragma unroll
    for (int v = 0; v < NV; ++v) {
      float4 a4 = *reinterpret_cast<const float4*>(&xl[(long)s * TC + base + v * 4]);
      float4 r4 = *reinterpret_cast<const float4*>(&xr[(long)d * TC + base + v * 4]);
      float aa[4] = {a4.x, a4.y, a4.z, a4.w};
      float rr[4] = {r4.x, r4.y, r4.z, r4.w};
      #pragma unroll
      for (int q = 0; q < 4; ++q) {
        float t = aa[q] + rr[q];
        t = t > 0.f ? t : 0.2f * t;            // leaky_relu(0.2)
        partial = fmaf(t, attv[v * 4 + q], partial);
        xs[v * 4 + q] = aa[q];
      }
    }
    #pragma unroll
    for (int o = 1; o < GRP; o <<= 1)
      partial += __shfl_xor(partial, o, 64);
    float w = __expf(partial);
    if ((lane & (GRP - 1)) == 0) atomicAdd(&denom[(long)d * H + head], w);
    #pragma unroll
    for (int p = 0; p < PER; ++p)
      atomicAdd(&acc[(long)d * TC + base + p], w * xs[p]);
  }
}

// ---------------- Finalize: acc = acc/denom + bias ----------------
template<int H>
__global__ __launch_bounds__(256) void finalize(float* __restrict__ acc,
    const float* __restrict__ denom, const float* __restrict__ bias) {
  constexpr int TC = H * 128;
  long idx = (long)blockIdx.x * blockDim.x + threadIdx.x;
  if (idx >= (long)N_NODES * TC) return;
  int i = (int)(idx / TC);
  int t = (int)(idx % TC);
  int h = t >> 7;
  acc[idx] = acc[idx] / denom[(long)i * H + h] + bias[t];
}

extern "C" void kernel_launch(void* const* d_in, const int* in_sizes, int n_in,
                              void* d_out, int out_size, void* d_ws, size_t ws_size,
                              hipStream_t stream) {
  const float* x    = (const float*)d_in[0];
  const int*   ei   = (const int*)d_in[1];   // [2, E_LOCAL]
  const int*   gei  = (const int*)d_in[2];   // [2, E_GLOBAL]
  const float* Wl1  = (const float*)d_in[3];
  const float* bl1  = (const float*)d_in[4];
  const float* Wr1  = (const float*)d_in[5];
  const float* br1  = (const float*)d_in[6];
  const float* att1 = (const float*)d_in[7];
  const float* b1   = (const float*)d_in[8];
  const float* Wl2  = (const float*)d_in[9];
  const float* bl2  = (const float*)d_in[10];
  const float* Wr2  = (const float*)d_in[11];
  const float* br2  = (const float*)d_in[12];
  const float* att2 = (const float*)d_in[13];
  const float* b2   = (const float*)d_in[14];
  const float* Wfc  = (const float*)d_in[15];
  const float* bfc  = (const float*)d_in[16];
  float* out = (float*)d_out;

  float* p = (float*)d_ws;
  float* xl1 = p;  p += (size_t)N_NODES * 512;
  float* xr1 = p;  p += (size_t)N_NODES * 512;
  float* xl2 = p;  p += (size_t)N_NODES * 256;
  float* xr2 = p;  p += (size_t)N_NODES * 256;
  float* acc1 = p; p += (size_t)N_NODES * 512;
  float* acc2 = p; p += (size_t)N_NODES * 256;
  float* den1 = p; p += (size_t)N_NODES * 4;
  float* den2 = p; p += (size_t)N_NODES * 2;

  // zero acc1|acc2|den1|den2 (contiguous)
  hipMemsetAsync(acc1, 0, (size_t)N_NODES * (512 + 256 + 6) * sizeof(float), stream);

  const int N = N_NODES;
  // Input transforms
  gemm_bias<128, false><<<dim3(8, 157), 256, 0, stream>>>(x, Wl1, bl1, xl1, N, 512);
  gemm_bias<128, false><<<dim3(8, 157), 256, 0, stream>>>(x, Wr1, br1, xr1, N, 512);
  gemm_bias<128, false><<<dim3(4, 157), 256, 0, stream>>>(x, Wl2, bl2, xl2, N, 256);
  gemm_bias<128, false><<<dim3(4, 157), 256, 0, stream>>>(x, Wr2, br2, xr2, N, 256);

  // Edge aggregation (unnormalized online softmax)
  edge_pass<4><<<2048, 256, 0, stream>>>(xl1, xr1, att1, ei, ei + E_LOCAL, E_LOCAL, acc1, den1);
  edge_pass<2><<<2048, 256, 0, stream>>>(xl2, xr2, att2, gei, gei + E_GLOBAL, E_GLOBAL, acc2, den2);

  // Normalize + bias
  finalize<4><<<(N_NODES * 512) / 256, 256, 0, stream>>>(acc1, den1, b1);
  finalize<2><<<(N_NODES * 256) / 256, 256, 0, stream>>>(acc2, den2, b2);

  // Final FC over concat = two accumulating GEMMs
  gemm_bias<512, false><<<dim3(2, 157), 256, 0, stream>>>(acc1, Wfc, bfc, out, N, 128);
  gemm_bias<256, true ><<<dim3(2, 157), 256, 0, stream>>>(acc2, Wfc + 512 * 128, nullptr, out, N, 128);
}

// Round 5
// 545.775 us; speedup vs baseline: 12.6223x; 12.6223x over previous
//
#include <hip/hip_runtime.h>

#define N_NODES 10000
#define E_LOCAL 320000
#define E_GLOBAL 640000
#define CNT_LEN 10240   // padded count/offset array (>= N_NODES+1)

// ---------------- GEMM: out[N,M] = A[N,K] @ W[K,M] (+bias) (+=) ----------------
// 64x64 tile, 256 threads, 4x4 microtile per thread.
template<int K, bool ACCUM>
__global__ __launch_bounds__(256) void gemm_bias(const float* __restrict__ A,
    const float* __restrict__ W, const float* __restrict__ bias,
    float* __restrict__ out, int N, int M) {
  __shared__ float As[16][64];   // As[k][row]
  __shared__ float Ws[16][64];   // Ws[k][col]
  const int tid = threadIdx.x;
  const int tx = tid & 15;       // col group
  const int ty = tid >> 4;       // row group
  const int row0 = blockIdx.y * 64;
  const int col0 = blockIdx.x * 64;
  const int lr = tid >> 2;       // A row within tile (0..63)
  const int lk = tid & 3;        // A float4 index within 16-k chunk
  const int wr = tid >> 4;       // W k-row (0..15)
  const int wc = tid & 15;       // W float4 col
  float acc[4][4] = {};
  for (int k0 = 0; k0 < K; k0 += 16) {
    int gr = row0 + lr; if (gr >= N) gr = N - 1;   // clamp (stores are guarded)
    float4 av = *reinterpret_cast<const float4*>(&A[(long)gr * K + k0 + lk * 4]);
    float4 wv = *reinterpret_cast<const float4*>(&W[(long)(k0 + wr) * M + col0 + wc * 4]);
    __syncthreads();
    As[lk * 4 + 0][lr] = av.x;
    As[lk * 4 + 1][lr] = av.y;
    As[lk * 4 + 2][lr] = av.z;
    As[lk * 4 + 3][lr] = av.w;
    *reinterpret_cast<float4*>(&Ws[wr][wc * 4]) = wv;
    __syncthreads();
    #pragma unroll
    for (int k = 0; k < 16; ++k) {
      float4 a4 = *reinterpret_cast<const float4*>(&As[k][ty * 4]);
      float4 b4 = *reinterpret_cast<const float4*>(&Ws[k][tx * 4]);
      float aa[4] = {a4.x, a4.y, a4.z, a4.w};
      float bb[4] = {b4.x, b4.y, b4.z, b4.w};
      #pragma unroll
      for (int i = 0; i < 4; ++i)
        #pragma unroll
        for (int j = 0; j < 4; ++j)
          acc[i][j] = fmaf(aa[i], bb[j], acc[i][j]);
    }
  }
  #pragma unroll
  for (int i = 0; i < 4; ++i) {
    int r = row0 + ty * 4 + i;
    if (r >= N) continue;
    #pragma unroll
    for (int j = 0; j < 4; ++j) {
      int c = col0 + tx * 4 + j;
      float v = acc[i][j];
      if (bias) v += bias[c];
      if (ACCUM) out[(long)r * M + c] += v;
      else       out[(long)r * M + c] = v;
    }
  }
}

// ---------------- CSR build: histogram -> scan -> scatter ----------------
__global__ __launch_bounds__(256) void hist_kernel(const int* __restrict__ dsts,
    int E, int* __restrict__ cnt) {
  int i = blockIdx.x * blockDim.x + threadIdx.x;
  if (i < E) atomicAdd(&cnt[dsts[i]], 1);
}

// Single workgroup exclusive scan over CNT_LEN ints, in place; also copies to cur.
__global__ __launch_bounds__(256) void scan_kernel(int* __restrict__ cnt,
    int* __restrict__ cur) {
  __shared__ int sums[256];
  const int t = threadIdx.x;
  const int CH = CNT_LEN / 256;   // 40
  int s = 0;
  for (int j = 0; j < CH; ++j) s += cnt[t * CH + j];
  sums[t] = s;
  __syncthreads();
  for (int o = 1; o < 256; o <<= 1) {
    int v = (t >= o) ? sums[t - o] : 0;
    __syncthreads();
    sums[t] += v;
    __syncthreads();
  }
  int prefix = (t == 0) ? 0 : sums[t - 1];
  for (int j = 0; j < CH; ++j) {
    int idx = t * CH + j;
    int c = cnt[idx];
    cnt[idx] = prefix;
    cur[idx] = prefix;
    prefix += c;
  }
}

__global__ __launch_bounds__(256) void scatter_kernel(const int* __restrict__ srcs,
    const int* __restrict__ dsts, int E, int* __restrict__ cur,
    int* __restrict__ csr) {
  int i = blockIdx.x * blockDim.x + threadIdx.x;
  if (i < E) {
    int pos = atomicAdd(&cur[dsts[i]], 1);
    csr[pos] = srcs[i];
  }
}

// ---------------- Node-stationary aggregation (no float atomics) ----------------
// One wave per node. acc/den in registers. Self-loop folded in. Fuses finalize.
template<int H>
__global__ __launch_bounds__(256) void aggregate(
    const float* __restrict__ xl, const float* __restrict__ xr,
    const float* __restrict__ att, const int* __restrict__ csr,
    const int* __restrict__ off, const float* __restrict__ bias,
    float* __restrict__ outp) {
  constexpr int TC = H * 128;      // total channels
  constexpr int PER = TC / 64;     // floats per lane
  constexpr int NV = PER / 4;      // float4s per lane
  constexpr int GRP = 64 / H;      // lanes per head
  const int lane = threadIdx.x & 63;
  const int node = (int)(((long)blockIdx.x * blockDim.x + threadIdx.x) >> 6);
  if (node >= N_NODES) return;
  const int base = lane * PER;

  float attv[PER], xri[PER], acc[PER];
  #pragma unroll
  for (int p = 0; p < PER; ++p) attv[p] = att[base + p];
  #pragma unroll
  for (int v = 0; v < NV; ++v) {
    float4 r4 = *reinterpret_cast<const float4*>(&xr[(long)node * TC + base + v * 4]);
    xri[v*4+0] = r4.x; xri[v*4+1] = r4.y; xri[v*4+2] = r4.z; xri[v*4+3] = r4.w;
  }

  // self-loop message (src == dst == node)
  float den;
  {
    float xs[PER]; float part = 0.f;
    #pragma unroll
    for (int v = 0; v < NV; ++v) {
      float4 a4 = *reinterpret_cast<const float4*>(&xl[(long)node * TC + base + v * 4]);
      float aa[4] = {a4.x, a4.y, a4.z, a4.w};
      #pragma unroll
      for (int q = 0; q < 4; ++q) {
        float t = aa[q] + xri[v*4+q];
        t = t > 0.f ? t : 0.2f * t;
        part = fmaf(t, attv[v*4+q], part);
        xs[v*4+q] = aa[q];
      }
    }
    #pragma unroll
    for (int o = 1; o < GRP; o <<= 1) part += __shfl_xor(part, o, 64);
    den = __expf(part);
    #pragma unroll
    for (int p = 0; p < PER; ++p) acc[p] = den * xs[p];
  }

  const int e1 = off[node + 1];
  int e = off[node];
  // unroll-2: two independent gather+dot chains in flight
  for (; e + 2 <= e1; e += 2) {
    const int s0 = csr[e], s1 = csr[e + 1];
    float xs0[PER], xs1[PER];
    #pragma unroll
    for (int v = 0; v < NV; ++v) {
      float4 a4 = *reinterpret_cast<const float4*>(&xl[(long)s0 * TC + base + v * 4]);
      xs0[v*4+0] = a4.x; xs0[v*4+1] = a4.y; xs0[v*4+2] = a4.z; xs0[v*4+3] = a4.w;
    }
    #pragma unroll
    for (int v = 0; v < NV; ++v) {
      float4 a4 = *reinterpret_cast<const float4*>(&xl[(long)s1 * TC + base + v * 4]);
      xs1[v*4+0] = a4.x; xs1[v*4+1] = a4.y; xs1[v*4+2] = a4.z; xs1[v*4+3] = a4.w;
    }
    float p0 = 0.f, p1 = 0.f;
    #pragma unroll
    for (int p = 0; p < PER; ++p) {
      float t0 = xs0[p] + xri[p]; t0 = t0 > 0.f ? t0 : 0.2f * t0;
      p0 = fmaf(t0, attv[p], p0);
      float t1 = xs1[p] + xri[p]; t1 = t1 > 0.f ? t1 : 0.2f * t1;
      p1 = fmaf(t1, attv[p], p1);
    }
    #pragma unroll
    for (int o = 1; o < GRP; o <<= 1) {
      p0 += __shfl_xor(p0, o, 64);
      p1 += __shfl_xor(p1, o, 64);
    }
    float w0 = __expf(p0), w1 = __expf(p1);
    den += w0 + w1;
    #pragma unroll
    for (int p = 0; p < PER; ++p)
      acc[p] = fmaf(w1, xs1[p], fmaf(w0, xs0[p], acc[p]));
  }
  if (e < e1) {
    const int s0 = csr[e];
    float xs0[PER]; float p0 = 0.f;
    #pragma unroll
    for (int v = 0; v < NV; ++v) {
      float4 a4 = *reinterpret_cast<const float4*>(&xl[(long)s0 * TC + base + v * 4]);
      float aa[4] = {a4.x, a4.y, a4.z, a4.w};
      #pragma unroll
      for (int q = 0; q < 4; ++q) {
        float t = aa[q] + xri[v*4+q];
        t = t > 0.f ? t : 0.2f * t;
        p0 = fmaf(t, attv[v*4+q], p0);
        xs0[v*4+q] = aa[q];
      }
    }
    #pragma unroll
    for (int o = 1; o < GRP; o <<= 1) p0 += __shfl_xor(p0, o, 64);
    float w0 = __expf(p0);
    den += w0;
    #pragma unroll
    for (int p = 0; p < PER; ++p) acc[p] = fmaf(w0, xs0[p], acc[p]);
  }

  const float inv = 1.f / den;
  #pragma unroll
  for (int p = 0; p < PER; ++p)
    outp[(long)node * TC + base + p] = fmaf(acc[p], inv, bias[base + p]);
}

extern "C" void kernel_launch(void* const* d_in, const int* in_sizes, int n_in,
                              void* d_out, int out_size, void* d_ws, size_t ws_size,
                              hipStream_t stream) {
  const float* x    = (const float*)d_in[0];
  const int*   ei   = (const int*)d_in[1];   // [2, E_LOCAL]
  const int*   gei  = (const int*)d_in[2];   // [2, E_GLOBAL]
  const float* Wl1  = (const float*)d_in[3];
  const float* bl1  = (const float*)d_in[4];
  const float* Wr1  = (const float*)d_in[5];
  const float* br1  = (const float*)d_in[6];
  const float* att1 = (const float*)d_in[7];
  const float* b1   = (const float*)d_in[8];
  const float* Wl2  = (const float*)d_in[9];
  const float* bl2  = (const float*)d_in[10];
  const float* Wr2  = (const float*)d_in[11];
  const float* br2  = (const float*)d_in[12];
  const float* att2 = (const float*)d_in[13];
  const float* b2   = (const float*)d_in[14];
  const float* Wfc  = (const float*)d_in[15];
  const float* bfc  = (const float*)d_in[16];
  float* out = (float*)d_out;

  float* p = (float*)d_ws;
  float* xl1 = p;  p += (size_t)N_NODES * 512;
  float* xr1 = p;  p += (size_t)N_NODES * 512;
  float* xl2 = p;  p += (size_t)N_NODES * 256;
  float* xr2 = p;  p += (size_t)N_NODES * 256;
  float* h1  = p;  p += (size_t)N_NODES * 512;
  float* h2  = p;  p += (size_t)N_NODES * 256;
  int* off1 = (int*)p;          // CNT_LEN
  int* off2 = off1 + CNT_LEN;
  int* cur1 = off2 + CNT_LEN;
  int* cur2 = cur1 + CNT_LEN;
  int* csr1 = cur2 + CNT_LEN;   // E_LOCAL
  int* csr2 = csr1 + E_LOCAL;   // E_GLOBAL

  // zero the two count arrays (contiguous)
  hipMemsetAsync(off1, 0, 2 * CNT_LEN * sizeof(int), stream);

  const int N = N_NODES;
  // Input transforms
  gemm_bias<128, false><<<dim3(8, 157), 256, 0, stream>>>(x, Wl1, bl1, xl1, N, 512);
  gemm_bias<128, false><<<dim3(8, 157), 256, 0, stream>>>(x, Wr1, br1, xr1, N, 512);
  gemm_bias<128, false><<<dim3(4, 157), 256, 0, stream>>>(x, Wl2, bl2, xl2, N, 256);
  gemm_bias<128, false><<<dim3(4, 157), 256, 0, stream>>>(x, Wr2, br2, xr2, N, 256);

  // CSR build (by destination)
  hist_kernel<<<(E_LOCAL + 255) / 256, 256, 0, stream>>>(ei + E_LOCAL, E_LOCAL, off1);
  hist_kernel<<<(E_GLOBAL + 255) / 256, 256, 0, stream>>>(gei + E_GLOBAL, E_GLOBAL, off2);
  scan_kernel<<<1, 256, 0, stream>>>(off1, cur1);
  scan_kernel<<<1, 256, 0, stream>>>(off2, cur2);
  scatter_kernel<<<(E_LOCAL + 255) / 256, 256, 0, stream>>>(ei, ei + E_LOCAL, E_LOCAL, cur1, csr1);
  scatter_kernel<<<(E_GLOBAL + 255) / 256, 256, 0, stream>>>(gei, gei + E_GLOBAL, E_GLOBAL, cur2, csr2);

  // Node-stationary aggregation (fuses softmax-normalize + bias)
  aggregate<4><<<(N * 64 + 255) / 256, 256, 0, stream>>>(xl1, xr1, att1, csr1, off1, b1, h1);
  aggregate<2><<<(N * 64 + 255) / 256, 256, 0, stream>>>(xl2, xr2, att2, csr2, off2, b2, h2);

  // Final FC over concat = two accumulating GEMMs
  gemm_bias<512, false><<<dim3(2, 157), 256, 0, stream>>>(h1, Wfc, bfc, out, N, 128);
  gemm_bias<256, true ><<<dim3(2, 157), 256, 0, stream>>>(h2, Wfc + 512 * 128, nullptr, out, N, 128);
}

// Round 8
// 407.465 us; speedup vs baseline: 16.9068x; 1.3394x over previous
//
#include <hip/hip_runtime.h>

#define N_NODES 10000
#define E_LOCAL 320000
#define E_GLOBAL 640000
#define CNT_LEN 10240   // padded count/offset array (>= N_NODES+1)
#define LDSW 40         // ushorts per LDS row (80 B stride: 16B-aligned, ~2-way banks)

typedef __attribute__((ext_vector_type(8))) short short8;
typedef __attribute__((ext_vector_type(4))) float f32x4;
typedef __attribute__((ext_vector_type(4))) unsigned short ushort4v;

__device__ __forceinline__ float bf2f(unsigned short u) {
  union { unsigned int i; float f; } v; v.i = ((unsigned int)u) << 16; return v.f;
}
__device__ __forceinline__ unsigned short f2bf(float f) {
  union { unsigned int i; float f; } v; v.f = f;
  unsigned int r = (v.i + 0x7FFF + ((v.i >> 16) & 1)) >> 16;
  return (unsigned short)r;
}

// ---------------- conversions ----------------
__global__ __launch_bounds__(256) void f32_to_bf16_vec(const float* __restrict__ in,
    ushort* __restrict__ out, int n4) {
  int i = blockIdx.x * blockDim.x + threadIdx.x;
  if (i < n4) {
    float4 f = reinterpret_cast<const float4*>(in)[i];
    ushort4v o; o[0] = f2bf(f.x); o[1] = f2bf(f.y); o[2] = f2bf(f.z); o[3] = f2bf(f.w);
    reinterpret_cast<ushort4v*>(out)[i] = o;
  }
}

// Wt[n][k] = bf16(W[k][n])
__global__ __launch_bounds__(256) void transpose_bf16(const float* __restrict__ W,
    ushort* __restrict__ Wt, int K, int N) {
  int i = blockIdx.x * blockDim.x + threadIdx.x;
  if (i < K * N) { int k = i / N, n = i - k * N; Wt[(size_t)n * K + k] = f2bf(W[i]); }
}

// ---------------- MFMA GEMM: out[M,N] = A[M,K](bf16) @ Bt[N,K]^T (+bias) ----------------
// 64x64 tile, 4 waves, 16x16x32 bf16 MFMA. Single-buffer LDS.
template<bool OUT_BF16>
__global__ __launch_bounds__(256) void gemm_mfma(
    const ushort* __restrict__ A,   // [M][K] bf16 row-major
    const ushort* __restrict__ Bt,  // [N][K] bf16 row-major (B transposed)
    const float* __restrict__ bias, // [N] or nullptr
    void* __restrict__ outv, int M, int N, int K, int ldOut) {
  __shared__ ushort As[64 * LDSW];
  __shared__ ushort Bs[64 * LDSW];
  const int tid  = threadIdx.x;
  const int wave = tid >> 6;
  const int lane = tid & 63;
  const int row0 = blockIdx.y * 64;
  const int col0 = blockIdx.x * 64;
  // staging: thread loads one 16B chunk of A-tile and one of B-tile per k-step
  const int sr = tid >> 2;          // 0..63: A row / Bt row (n)
  const int sc = tid & 3;           // k-chunk of 8 bf16
  int ar = row0 + sr; if (ar >= M) ar = M - 1;     // clamp; stores guarded
  const ushort* Aptr = A  + (size_t)ar * K + sc * 8;
  const ushort* Bptr = Bt + (size_t)(col0 + sr) * K + sc * 8;
  // fragment indices
  const int fr = lane & 15;         // A row / B col within fragment
  const int kc = lane >> 4;         // k-chunk (8 elems)
  f32x4 c[4];
  #pragma unroll
  for (int f = 0; f < 4; ++f) { c[f][0]=0.f; c[f][1]=0.f; c[f][2]=0.f; c[f][3]=0.f; }

  for (int k0 = 0; k0 < K; k0 += 32) {
    __syncthreads();
    *reinterpret_cast<short8*>(&As[sr * LDSW + sc * 8]) =
        *reinterpret_cast<const short8*>(Aptr + k0);
    *reinterpret_cast<short8*>(&Bs[sr * LDSW + sc * 8]) =
        *reinterpret_cast<const short8*>(Bptr + k0);
    __syncthreads();
    short8 a = *reinterpret_cast<const short8*>(&As[(wave * 16 + fr) * LDSW + kc * 8]);
    #pragma unroll
    for (int f = 0; f < 4; ++f) {
      short8 b = *reinterpret_cast<const short8*>(&Bs[(f * 16 + fr) * LDSW + kc * 8]);
      c[f] = __builtin_amdgcn_mfma_f32_16x16x32_bf16(a, b, c[f], 0, 0, 0);
    }
  }
  // epilogue: C/D layout col=lane&15, row=(lane>>4)*4+reg  [m89-verified]
  const int orow = row0 + wave * 16 + (lane >> 4) * 4;
  #pragma unroll
  for (int f = 0; f < 4; ++f) {
    const int col = col0 + f * 16 + fr;
    const float bv = bias ? bias[col] : 0.f;
    #pragma unroll
    for (int q = 0; q < 4; ++q) {
      const int r = orow + q;
      if (r < M) {
        float v = c[f][q] + bv;
        if (OUT_BF16) ((ushort*)outv)[(size_t)r * ldOut + col] = f2bf(v);
        else          ((float*) outv)[(size_t)r * ldOut + col] = v;
      }
    }
  }
}

// ---------------- CSR build: histogram -> scan -> scatter ----------------
__global__ __launch_bounds__(256) void hist_kernel(const int* __restrict__ dsts,
    int E, int* __restrict__ cnt) {
  int i = blockIdx.x * blockDim.x + threadIdx.x;
  if (i < E) atomicAdd(&cnt[dsts[i]], 1);
}

__global__ __launch_bounds__(256) void scan_kernel(int* __restrict__ cnt,
    int* __restrict__ cur) {
  __shared__ int sums[256];
  const int t = threadIdx.x;
  const int CH = CNT_LEN / 256;   // 40
  int s = 0;
  for (int j = 0; j < CH; ++j) s += cnt[t * CH + j];
  sums[t] = s;
  __syncthreads();
  for (int o = 1; o < 256; o <<= 1) {
    int v = (t >= o) ? sums[t - o] : 0;
    __syncthreads();
    sums[t] += v;
    __syncthreads();
  }
  int prefix = (t == 0) ? 0 : sums[t - 1];
  for (int j = 0; j < CH; ++j) {
    int idx = t * CH + j;
    int c = cnt[idx];
    cnt[idx] = prefix;
    cur[idx] = prefix;
    prefix += c;
  }
}

__global__ __launch_bounds__(256) void scatter_kernel(const int* __restrict__ srcs,
    const int* __restrict__ dsts, int E, int* __restrict__ cur,
    int* __restrict__ csr) {
  int i = blockIdx.x * blockDim.x + threadIdx.x;
  if (i < E) {
    int pos = atomicAdd(&cur[dsts[i]], 1);
    csr[pos] = srcs[i];
  }
}

// ---------------- Node-stationary aggregation (bf16 tables, f32 math) ----------------
// One wave per node. Fuses softmax-normalize + bias; writes bf16 into concat buffer.
template<int H>
__global__ __launch_bounds__(256) void aggregate(
    const ushort* __restrict__ xl, const ushort* __restrict__ xr,
    const float* __restrict__ att, const int* __restrict__ csr,
    const int* __restrict__ off, const float* __restrict__ bias,
    ushort* __restrict__ outp, int outLd) {
  constexpr int TC = H * 128;      // total channels
  constexpr int PER = TC / 64;     // elems per lane (8 for H=4, 4 for H=2)
  constexpr int NV = PER / 4;      // ushort4 loads per lane
  constexpr int GRP = 64 / H;      // lanes per head
  const int lane = threadIdx.x & 63;
  const int node = (int)(((long)blockIdx.x * blockDim.x + threadIdx.x) >> 6);
  if (node >= N_NODES) return;
  const int base = lane * PER;

  float attv[PER], xri[PER], acc[PER];
  #pragma unroll
  for (int p = 0; p < PER; ++p) attv[p] = att[base + p];
  #pragma unroll
  for (int v = 0; v < NV; ++v) {
    ushort4v u = *reinterpret_cast<const ushort4v*>(&xr[(size_t)node * TC + base + v * 4]);
    #pragma unroll
    for (int q = 0; q < 4; ++q) xri[v * 4 + q] = bf2f(u[q]);
  }

  // self-loop message (src == dst == node)
  float den;
  {
    float xs[PER]; float part = 0.f;
    #pragma unroll
    for (int v = 0; v < NV; ++v) {
      ushort4v u = *reinterpret_cast<const ushort4v*>(&xl[(size_t)node * TC + base + v * 4]);
      #pragma unroll
      for (int q = 0; q < 4; ++q) {
        float a = bf2f(u[q]);
        float t = a + xri[v * 4 + q];
        t = t > 0.f ? t : 0.2f * t;
        part = fmaf(t, attv[v * 4 + q], part);
        xs[v * 4 + q] = a;
      }
    }
    #pragma unroll
    for (int o = 1; o < GRP; o <<= 1) part += __shfl_xor(part, o, 64);
    den = __expf(part);
    #pragma unroll
    for (int p = 0; p < PER; ++p) acc[p] = den * xs[p];
  }

  const int e1 = off[node + 1];
  int e = off[node];
  for (; e + 2 <= e1; e += 2) {
    const int s0 = csr[e], s1 = csr[e + 1];
    float xs0[PER], xs1[PER];
    #pragma unroll
    for (int v = 0; v < NV; ++v) {
      ushort4v u = *reinterpret_cast<const ushort4v*>(&xl[(size_t)s0 * TC + base + v * 4]);
      #pragma unroll
      for (int q = 0; q < 4; ++q) xs0[v * 4 + q] = bf2f(u[q]);
    }
    #pragma unroll
    for (int v = 0; v < NV; ++v) {
      ushort4v u = *reinterpret_cast<const ushort4v*>(&xl[(size_t)s1 * TC + base + v * 4]);
      #pragma unroll
      for (int q = 0; q < 4; ++q) xs1[v * 4 + q] = bf2f(u[q]);
    }
    float p0 = 0.f, p1 = 0.f;
    #pragma unroll
    for (int p = 0; p < PER; ++p) {
      float t0 = xs0[p] + xri[p]; t0 = t0 > 0.f ? t0 : 0.2f * t0;
      p0 = fmaf(t0, attv[p], p0);
      float t1 = xs1[p] + xri[p]; t1 = t1 > 0.f ? t1 : 0.2f * t1;
      p1 = fmaf(t1, attv[p], p1);
    }
    #pragma unroll
    for (int o = 1; o < GRP; o <<= 1) {
      p0 += __shfl_xor(p0, o, 64);
      p1 += __shfl_xor(p1, o, 64);
    }
    float w0 = __expf(p0), w1 = __expf(p1);
    den += w0 + w1;
    #pragma unroll
    for (int p = 0; p < PER; ++p)
      acc[p] = fmaf(w1, xs1[p], fmaf(w0, xs0[p], acc[p]));
  }
  if (e < e1) {
    const int s0 = csr[e];
    float xs0[PER]; float p0 = 0.f;
    #pragma unroll
    for (int v = 0; v < NV; ++v) {
      ushort4v u = *reinterpret_cast<const ushort4v*>(&xl[(size_t)s0 * TC + base + v * 4]);
      #pragma unroll
      for (int q = 0; q < 4; ++q) {
        float a = bf2f(u[q]);
        float t = a + xri[v * 4 + q];
        t = t > 0.f ? t : 0.2f * t;
        p0 = fmaf(t, attv[v * 4 + q], p0);
        xs0[v * 4 + q] = a;
      }
    }
    #pragma unroll
    for (int o = 1; o < GRP; o <<= 1) p0 += __shfl_xor(p0, o, 64);
    float w0 = __expf(p0);
    den += w0;
    #pragma unroll
    for (int p = 0; p < PER; ++p) acc[p] = fmaf(w0, xs0[p], acc[p]);
  }

  const float inv = 1.f / den;
  #pragma unroll
  for (int v = 0; v < NV; ++v) {
    ushort4v o;
    #pragma unroll
    for (int q = 0; q < 4; ++q)
      o[q] = f2bf(fmaf(acc[v * 4 + q], inv, bias[base + v * 4 + q]));
    *reinterpret_cast<ushort4v*>(&outp[(size_t)node * outLd + base + v * 4]) = o;
  }
}

extern "C" void kernel_launch(void* const* d_in, const int* in_sizes, int n_in,
                              void* d_out, int out_size, void* d_ws, size_t ws_size,
                              hipStream_t stream) {
  const float* x    = (const float*)d_in[0];
  const int*   ei   = (const int*)d_in[1];   // [2, E_LOCAL]
  const int*   gei  = (const int*)d_in[2];   // [2, E_GLOBAL]
  const float* Wl1  = (const float*)d_in[3];
  const float* bl1  = (const float*)d_in[4];
  const float* Wr1  = (const float*)d_in[5];
  const float* br1  = (const float*)d_in[6];
  const float* att1 = (const float*)d_in[7];
  const float* b1   = (const float*)d_in[8];
  const float* Wl2  = (const float*)d_in[9];
  const float* bl2  = (const float*)d_in[10];
  const float* Wr2  = (const float*)d_in[11];
  const float* br2  = (const float*)d_in[12];
  const float* att2 = (const float*)d_in[13];
  const float* b2   = (const float*)d_in[14];
  const float* Wfc  = (const float*)d_in[15];
  const float* bfc  = (const float*)d_in[16];
  float* out = (float*)d_out;

  char* w = (char*)d_ws;
  ushort* xb    = (ushort*)w; w += (size_t)N_NODES * 128 * 2;
  ushort* xl1b  = (ushort*)w; w += (size_t)N_NODES * 512 * 2;
  ushort* xr1b  = (ushort*)w; w += (size_t)N_NODES * 512 * 2;
  ushort* xl2b  = (ushort*)w; w += (size_t)N_NODES * 256 * 2;
  ushort* xr2b  = (ushort*)w; w += (size_t)N_NODES * 256 * 2;
  ushort* hb    = (ushort*)w; w += (size_t)N_NODES * 768 * 2;   // concat [N][768]
  ushort* wtl1  = (ushort*)w; w += (size_t)512 * 128 * 2;
  ushort* wtr1  = (ushort*)w; w += (size_t)512 * 128 * 2;
  ushort* wtl2  = (ushort*)w; w += (size_t)256 * 128 * 2;
  ushort* wtr2  = (ushort*)w; w += (size_t)256 * 128 * 2;
  ushort* wtfc  = (ushort*)w; w += (size_t)128 * 768 * 2;
  int* off1 = (int*)w;
  int* off2 = off1 + CNT_LEN;
  int* cur1 = off2 + CNT_LEN;
  int* cur2 = cur1 + CNT_LEN;
  int* csr1 = cur2 + CNT_LEN;   // E_LOCAL
  int* csr2 = csr1 + E_LOCAL;   // E_GLOBAL

  hipMemsetAsync(off1, 0, 2 * CNT_LEN * sizeof(int), stream);

  const int N = N_NODES;
  // bf16 conversions
  f32_to_bf16_vec<<<(N * 128 / 4 + 255) / 256, 256, 0, stream>>>(x, xb, N * 128 / 4);
  transpose_bf16<<<(128 * 512 + 255) / 256, 256, 0, stream>>>(Wl1, wtl1, 128, 512);
  transpose_bf16<<<(128 * 512 + 255) / 256, 256, 0, stream>>>(Wr1, wtr1, 128, 512);
  transpose_bf16<<<(128 * 256 + 255) / 256, 256, 0, stream>>>(Wl2, wtl2, 128, 256);
  transpose_bf16<<<(128 * 256 + 255) / 256, 256, 0, stream>>>(Wr2, wtr2, 128, 256);
  transpose_bf16<<<(768 * 128 + 255) / 256, 256, 0, stream>>>(Wfc, wtfc, 768, 128);

  // CSR build (by destination) — overlaps with transforms
  hist_kernel<<<(E_LOCAL + 255) / 256, 256, 0, stream>>>(ei + E_LOCAL, E_LOCAL, off1);
  hist_kernel<<<(E_GLOBAL + 255) / 256, 256, 0, stream>>>(gei + E_GLOBAL, E_GLOBAL, off2);
  scan_kernel<<<1, 256, 0, stream>>>(off1, cur1);
  scan_kernel<<<1, 256, 0, stream>>>(off2, cur2);
  scatter_kernel<<<(E_LOCAL + 255) / 256, 256, 0, stream>>>(ei, ei + E_LOCAL, E_LOCAL, cur1, csr1);
  scatter_kernel<<<(E_GLOBAL + 255) / 256, 256, 0, stream>>>(gei, gei + E_GLOBAL, E_GLOBAL, cur2, csr2);

  // Input transforms (MFMA bf16)
  gemm_mfma<true><<<dim3(8, 157), 256, 0, stream>>>(xb, wtl1, bl1, xl1b, N, 512, 128, 512);
  gemm_mfma<true><<<dim3(8, 157), 256, 0, stream>>>(xb, wtr1, br1, xr1b, N, 512, 128, 512);
  gemm_mfma<true><<<dim3(4, 157), 256, 0, stream>>>(xb, wtl2, bl2, xl2b, N, 256, 128, 256);
  gemm_mfma<true><<<dim3(4, 157), 256, 0, stream>>>(xb, wtr2, br2, xr2b, N, 256, 128, 256);

  // Node-stationary aggregation -> concat buffer hb [N][768]
  aggregate<4><<<(N * 64 + 255) / 256, 256, 0, stream>>>(xl1b, xr1b, att1, csr1, off1, b1, hb, 768);
  aggregate<2><<<(N * 64 + 255) / 256, 256, 0, stream>>>(xl2b, xr2b, att2, csr2, off2, b2, hb + 512, 768);

  // Final FC: one MFMA GEMM over concat, f32 out
  gemm_mfma<false><<<dim3(2, 157), 256, 0, stream>>>(hb, wtfc, bfc, out, N, 128, 768, 128);
}

// Round 9
// 357.815 us; speedup vs baseline: 19.2527x; 1.1388x over previous
//
#include <hip/hip_runtime.h>

#define N_NODES 10000
#define E_LOCAL 320000
#define E_GLOBAL 640000
#define CNT_LEN 10240   // padded count/offset array (>= N_NODES+1)

typedef __attribute__((ext_vector_type(8))) short short8;
typedef __attribute__((ext_vector_type(4))) float f32x4;
typedef __attribute__((ext_vector_type(4))) unsigned short ushort4v;
typedef __attribute__((ext_vector_type(2))) unsigned int uint2v;
typedef __attribute__((ext_vector_type(4))) unsigned int uint4v;

typedef __attribute__((address_space(1))) const void* gas_ptr;
typedef __attribute__((address_space(3))) void* lds_ptr;

__device__ __forceinline__ float bf2f(unsigned short u) {
  union { unsigned int i; float f; } v; v.i = ((unsigned int)u) << 16; return v.f;
}
__device__ __forceinline__ unsigned short f2bf(float f) {
  union { unsigned int i; float f; } v; v.f = f;
  unsigned int r = (v.i + 0x7FFF + ((v.i >> 16) & 1)) >> 16;
  return (unsigned short)r;
}
__device__ __forceinline__ void gld_lds16(const void* g, void* l) {
  __builtin_amdgcn_global_load_lds((gas_ptr)g, (lds_ptr)l, 16, 0, 0);
}

template<int NW> struct WVecT;
template<> struct WVecT<4> { using T = uint4v; };
template<> struct WVecT<2> { using T = uint2v; };

// word (2 bf16) -> 2 floats: lo = shl16, hi = mask
template<int NW, typename WV>
__device__ __forceinline__ void w2f(WV w, float* f) {
  #pragma unroll
  for (int i = 0; i < NW; ++i) {
    union { unsigned int u; float x; } lo, hi;
    lo.u = w[i] << 16; hi.u = w[i] & 0xffff0000u;
    f[2 * i] = lo.x; f[2 * i + 1] = hi.x;
  }
}

// ---------------- prep: x->bf16 + all weight transposes, one kernel ----------------
__global__ __launch_bounds__(256) void prep(
    const float* __restrict__ x,
    const float* __restrict__ Wl1, const float* __restrict__ Wr1,
    const float* __restrict__ Wl2, const float* __restrict__ Wr2,
    const float* __restrict__ Wfc,
    ushort* __restrict__ xb,
    ushort* __restrict__ wtl1, ushort* __restrict__ wtr1,
    ushort* __restrict__ wtl2, ushort* __restrict__ wtr2,
    ushort* __restrict__ wtfc) {
  int b = blockIdx.x;
  if (b < 1250) {                       // x conversion: 320000 float4 groups
    int i = b * 256 + threadIdx.x;
    if (i < 320000) {
      float4 f = reinterpret_cast<const float4*>(x)[i];
      ushort4v o; o[0] = f2bf(f.x); o[1] = f2bf(f.y); o[2] = f2bf(f.z); o[3] = f2bf(f.w);
      reinterpret_cast<ushort4v*>(xb)[i] = o;
    }
    return;
  }
  b -= 1250;
  const float* W; ushort* Wt; int K, N;
  if (b < 256)      { W = Wl1; Wt = wtl1; K = 128; N = 512; }
  else if (b < 512) { W = Wr1; Wt = wtr1; K = 128; N = 512; b -= 256; }
  else if (b < 640) { W = Wl2; Wt = wtl2; K = 128; N = 256; b -= 512; }
  else if (b < 768) { W = Wr2; Wt = wtr2; K = 128; N = 256; b -= 640; }
  else              { W = Wfc; Wt = wtfc; K = 768; N = 128; b -= 768; }
  int i = b * 256 + threadIdx.x;
  if (i < K * N) { int k = i / N, n = i - k * N; Wt[(size_t)n * K + k] = f2bf(W[i]); }
}

// ---------------- MFMA GEMM: out[M,N] = A[M,K] @ Bt[N,K]^T (+bias) ----------------
// 64x64 tile, 4 waves, global_load_lds(16B) staging, double-buffered LDS,
// one barrier per K-step.
template<bool OUT_BF16, int K>
__global__ __launch_bounds__(256) void gemm_mfma(
    const ushort* __restrict__ A,   // [M][K] bf16
    const ushort* __restrict__ Bt,  // [N][K] bf16 (B transposed)
    const float* __restrict__ bias, // [N] or nullptr
    void* __restrict__ outv, int M, int N, int ldOut) {
  __shared__ ushort As[2][64 * 32];
  __shared__ ushort Bs[2][64 * 32];
  const int tid  = threadIdx.x;
  const int wave = tid >> 6;
  const int lane = tid & 63;
  const int row0 = blockIdx.y * 64;
  const int col0 = blockIdx.x * 64;
  // staging: tid -> (row, 16B k-chunk); LDS dest linear tid*16B
  const int srow = tid >> 2;
  const int schunk = tid & 3;
  int ar = row0 + srow; if (ar >= M) ar = M - 1;   // clamp; stores guarded
  const ushort* aSrc = A  + (size_t)ar * K + schunk * 8;
  const ushort* bSrc = Bt + (size_t)(col0 + srow) * K + schunk * 8;
  const int ldsOff = tid * 8;   // ushorts (16 B per thread)
  const int fr = lane & 15;
  const int kc = lane >> 4;

  f32x4 c[4];
  #pragma unroll
  for (int f = 0; f < 4; ++f) { c[f][0] = 0.f; c[f][1] = 0.f; c[f][2] = 0.f; c[f][3] = 0.f; }

  constexpr int NK = K / 32;
  gld_lds16(aSrc, &As[0][ldsOff]);
  gld_lds16(bSrc, &Bs[0][ldsOff]);
  #pragma unroll
  for (int kk = 0; kk < NK; ++kk) {
    const int cur = kk & 1;
    __syncthreads();                       // drains vmcnt: buf[cur] ready; prior reads done
    if (kk + 1 < NK) {
      gld_lds16(aSrc + (kk + 1) * 32, &As[cur ^ 1][ldsOff]);
      gld_lds16(bSrc + (kk + 1) * 32, &Bs[cur ^ 1][ldsOff]);
    }
    short8 a = *reinterpret_cast<const short8*>(&As[cur][(wave * 16 + fr) * 32 + kc * 8]);
    #pragma unroll
    for (int f = 0; f < 4; ++f) {
      short8 b = *reinterpret_cast<const short8*>(&Bs[cur][(f * 16 + fr) * 32 + kc * 8]);
      c[f] = __builtin_amdgcn_mfma_f32_16x16x32_bf16(a, b, c[f], 0, 0, 0);
    }
  }
  // epilogue: C/D layout col=lane&15, row=(lane>>4)*4+reg  [m89-verified]
  const int orow = row0 + wave * 16 + (lane >> 4) * 4;
  #pragma unroll
  for (int f = 0; f < 4; ++f) {
    const int col = col0 + f * 16 + fr;
    const float bv = bias ? bias[col] : 0.f;
    #pragma unroll
    for (int q = 0; q < 4; ++q) {
      const int r = orow + q;
      if (r < M) {
        float v = c[f][q] + bv;
        if (OUT_BF16) ((ushort*)outv)[(size_t)r * ldOut + col] = f2bf(v);
        else          ((float*) outv)[(size_t)r * ldOut + col] = v;
      }
    }
  }
}

// ---------------- CSR build: merged histogram / scan / scatter ----------------
__global__ __launch_bounds__(256) void hist2(const int* __restrict__ dl,
    const int* __restrict__ dg, int* __restrict__ c1, int* __restrict__ c2) {
  int i = blockIdx.x * blockDim.x + threadIdx.x;
  if (i < E_LOCAL) atomicAdd(&c1[dl[i]], 1);
  else if (i < E_LOCAL + E_GLOBAL) atomicAdd(&c2[dg[i - E_LOCAL]], 1);
}

__global__ __launch_bounds__(256) void scan2(int* __restrict__ cnt1, int* __restrict__ cur1,
    int* __restrict__ cnt2, int* __restrict__ cur2) {
  int* cnt = blockIdx.x == 0 ? cnt1 : cnt2;
  int* cur = blockIdx.x == 0 ? cur1 : cur2;
  __shared__ int sums[256];
  const int t = threadIdx.x;
  const int CH = CNT_LEN / 256;   // 40
  int s = 0;
  for (int j = 0; j < CH; ++j) s += cnt[t * CH + j];
  sums[t] = s;
  __syncthreads();
  for (int o = 1; o < 256; o <<= 1) {
    int v = (t >= o) ? sums[t - o] : 0;
    __syncthreads();
    sums[t] += v;
    __syncthreads();
  }
  int prefix = (t == 0) ? 0 : sums[t - 1];
  for (int j = 0; j < CH; ++j) {
    int idx = t * CH + j;
    int c = cnt[idx];
    cnt[idx] = prefix;
    cur[idx] = prefix;
    prefix += c;
  }
}

__global__ __launch_bounds__(256) void scatter2(
    const int* __restrict__ sl, const int* __restrict__ dl,
    const int* __restrict__ sg, const int* __restrict__ dg,
    int* __restrict__ cur1, int* __restrict__ cur2,
    int* __restrict__ csr1, int* __restrict__ csr2) {
  int i = blockIdx.x * blockDim.x + threadIdx.x;
  if (i < E_LOCAL) {
    int pos = atomicAdd(&cur1[dl[i]], 1);
    csr1[pos] = sl[i];
  } else if (i < E_LOCAL + E_GLOBAL) {
    int j = i - E_LOCAL;
    int pos = atomicAdd(&cur2[dg[j]], 1);
    csr2[pos] = sg[j];
  }
}

// ---------------- Node-stationary aggregation (unroll-4 gather pipeline) ----------------
template<int H>
__global__ __launch_bounds__(256) void aggregate(
    const ushort* __restrict__ xl, const ushort* __restrict__ xr,
    const float* __restrict__ att, const int* __restrict__ csr,
    const int* __restrict__ off, const float* __restrict__ bias,
    ushort* __restrict__ outp, int outLd) {
  constexpr int TC = H * 128;      // total channels
  constexpr int PER = TC / 64;     // elems per lane (8 for H=4, 4 for H=2)
  constexpr int NW = PER / 2;      // 32-bit words per lane
  constexpr int GRP = 64 / H;      // lanes per head
  using WVec = typename WVecT<NW>::T;
  const int lane = threadIdx.x & 63;
  const int node = (int)(((long)blockIdx.x * blockDim.x + threadIdx.x) >> 6);
  if (node >= N_NODES) return;
  const int base = lane * PER;

  float attv[PER], xri[PER], acc[PER];
  #pragma unroll
  for (int p = 0; p < PER; ++p) attv[p] = att[base + p];
  {
    WVec r = *reinterpret_cast<const WVec*>(&xr[(size_t)node * TC + base]);
    w2f<NW>(r, xri);
  }

  // self-loop message (src == dst == node)
  float den;
  {
    float xs[PER]; float part = 0.f;
    WVec r = *reinterpret_cast<const WVec*>(&xl[(size_t)node * TC + base]);
    w2f<NW>(r, xs);
    #pragma unroll
    for (int p = 0; p < PER; ++p) {
      float t = xs[p] + xri[p];
      t = fmaxf(t, 0.2f * t);
      part = fmaf(t, attv[p], part);
    }
    #pragma unroll
    for (int o = 1; o < GRP; o <<= 1) part += __shfl_xor(part, o, 64);
    den = __expf(part);
    #pragma unroll
    for (int p = 0; p < PER; ++p) acc[p] = den * xs[p];
  }

  const int e1 = off[node + 1];
  int e = off[node];
  for (; e + 4 <= e1; e += 4) {
    WVec raw[4];
    #pragma unroll
    for (int m = 0; m < 4; ++m)
      raw[m] = *reinterpret_cast<const WVec*>(&xl[(size_t)csr[e + m] * TC + base]);
    #pragma unroll
    for (int m = 0; m < 4; ++m) {
      float xs[PER]; w2f<NW>(raw[m], xs);
      float pp = 0.f;
      #pragma unroll
      for (int p = 0; p < PER; ++p) {
        float t = xs[p] + xri[p];
        t = fmaxf(t, 0.2f * t);
        pp = fmaf(t, attv[p], pp);
      }
      #pragma unroll
      for (int o = 1; o < GRP; o <<= 1) pp += __shfl_xor(pp, o, 64);
      float w = __expf(pp);
      den += w;
      #pragma unroll
      for (int p = 0; p < PER; ++p) acc[p] = fmaf(w, xs[p], acc[p]);
    }
  }
  for (; e < e1; ++e) {
    WVec r = *reinterpret_cast<const WVec*>(&xl[(size_t)csr[e] * TC + base]);
    float xs[PER]; w2f<NW>(r, xs);
    float pp = 0.f;
    #pragma unroll
    for (int p = 0; p < PER; ++p) {
      float t = xs[p] + xri[p];
      t = fmaxf(t, 0.2f * t);
      pp = fmaf(t, attv[p], pp);
    }
    #pragma unroll
    for (int o = 1; o < GRP; o <<= 1) pp += __shfl_xor(pp, o, 64);
    float w = __expf(pp);
    den += w;
    #pragma unroll
    for (int p = 0; p < PER; ++p) acc[p] = fmaf(w, xs[p], acc[p]);
  }

  const float inv = 1.f / den;
  #pragma unroll
  for (int v = 0; v < PER / 4; ++v) {
    ushort4v o;
    #pragma unroll
    for (int q = 0; q < 4; ++q)
      o[q] = f2bf(fmaf(acc[v * 4 + q], inv, bias[base + v * 4 + q]));
    *reinterpret_cast<ushort4v*>(&outp[(size_t)node * outLd + base + v * 4]) = o;
  }
}

extern "C" void kernel_launch(void* const* d_in, const int* in_sizes, int n_in,
                              void* d_out, int out_size, void* d_ws, size_t ws_size,
                              hipStream_t stream) {
  const float* x    = (const float*)d_in[0];
  const int*   ei   = (const int*)d_in[1];   // [2, E_LOCAL]
  const int*   gei  = (const int*)d_in[2];   // [2, E_GLOBAL]
  const float* Wl1  = (const float*)d_in[3];
  const float* bl1  = (const float*)d_in[4];
  const float* Wr1  = (const float*)d_in[5];
  const float* br1  = (const float*)d_in[6];
  const float* att1 = (const float*)d_in[7];
  const float* b1   = (const float*)d_in[8];
  const float* Wl2  = (const float*)d_in[9];
  const float* bl2  = (const float*)d_in[10];
  const float* Wr2  = (const float*)d_in[11];
  const float* br2  = (const float*)d_in[12];
  const float* att2 = (const float*)d_in[13];
  const float* b2   = (const float*)d_in[14];
  const float* Wfc  = (const float*)d_in[15];
  const float* bfc  = (const float*)d_in[16];
  float* out = (float*)d_out;

  char* w = (char*)d_ws;
  ushort* xb    = (ushort*)w; w += (size_t)N_NODES * 128 * 2;
  ushort* xl1b  = (ushort*)w; w += (size_t)N_NODES * 512 * 2;
  ushort* xr1b  = (ushort*)w; w += (size_t)N_NODES * 512 * 2;
  ushort* xl2b  = (ushort*)w; w += (size_t)N_NODES * 256 * 2;
  ushort* xr2b  = (ushort*)w; w += (size_t)N_NODES * 256 * 2;
  ushort* hb    = (ushort*)w; w += (size_t)N_NODES * 768 * 2;   // concat [N][768]
  ushort* wtl1  = (ushort*)w; w += (size_t)512 * 128 * 2;
  ushort* wtr1  = (ushort*)w; w += (size_t)512 * 128 * 2;
  ushort* wtl2  = (ushort*)w; w += (size_t)256 * 128 * 2;
  ushort* wtr2  = (ushort*)w; w += (size_t)256 * 128 * 2;
  ushort* wtfc  = (ushort*)w; w += (size_t)128 * 768 * 2;
  int* off1 = (int*)w;
  int* off2 = off1 + CNT_LEN;
  int* cur1 = off2 + CNT_LEN;
  int* cur2 = cur1 + CNT_LEN;
  int* csr1 = cur2 + CNT_LEN;   // E_LOCAL
  int* csr2 = csr1 + E_LOCAL;   // E_GLOBAL

  hipMemsetAsync(off1, 0, 2 * CNT_LEN * sizeof(int), stream);

  const int N = N_NODES;
  // conversions + transposes (one kernel: 1250 + 1152 blocks)
  prep<<<2402, 256, 0, stream>>>(x, Wl1, Wr1, Wl2, Wr2, Wfc,
                                 xb, wtl1, wtr1, wtl2, wtr2, wtfc);

  // CSR build (by destination)
  hist2<<<(E_LOCAL + E_GLOBAL + 255) / 256, 256, 0, stream>>>(
      ei + E_LOCAL, gei + E_GLOBAL, off1, off2);
  scan2<<<2, 256, 0, stream>>>(off1, cur1, off2, cur2);
  scatter2<<<(E_LOCAL + E_GLOBAL + 255) / 256, 256, 0, stream>>>(
      ei, ei + E_LOCAL, gei, gei + E_GLOBAL, cur1, cur2, csr1, csr2);

  // Input transforms (MFMA bf16, gload_lds staging)
  gemm_mfma<true, 128><<<dim3(8, 157), 256, 0, stream>>>(xb, wtl1, bl1, xl1b, N, 512, 512);
  gemm_mfma<true, 128><<<dim3(8, 157), 256, 0, stream>>>(xb, wtr1, br1, xr1b, N, 512, 512);
  gemm_mfma<true, 128><<<dim3(4, 157), 256, 0, stream>>>(xb, wtl2, bl2, xl2b, N, 256, 256);
  gemm_mfma<true, 128><<<dim3(4, 157), 256, 0, stream>>>(xb, wtr2, br2, xr2b, N, 256, 256);

  // Node-stationary aggregation -> concat buffer hb [N][768]
  aggregate<4><<<(N * 64 + 255) / 256, 256, 0, stream>>>(xl1b, xr1b, att1, csr1, off1, b1, hb, 768);
  aggregate<2><<<(N * 64 + 255) / 256, 256, 0, stream>>>(xl2b, xr2b, att2, csr2, off2, b2, hb + 512, 768);

  // Final FC: one MFMA GEMM over concat, f32 out
  gemm_mfma<false, 768><<<dim3(2, 157), 256, 0, stream>>>(hb, wtfc, bfc, out, N, 128, 128);
}

// Round 11
// 345.356 us; speedup vs baseline: 19.9473x; 1.0361x over previous
//
#include <hip/hip_runtime.h>

#define N_NODES 10000
#define E_LOCAL 320000
#define E_GLOBAL 640000
#define CNT_LEN 10240   // padded count/offset array (>= N_NODES+1)

typedef __attribute__((ext_vector_type(8))) short short8;
typedef __attribute__((ext_vector_type(4))) float f32x4;
typedef __attribute__((ext_vector_type(4))) unsigned short ushort4v;
typedef __attribute__((ext_vector_type(2))) unsigned int uint2v;
typedef __attribute__((ext_vector_type(4))) unsigned int uint4v;

typedef __attribute__((address_space(1))) const void* gas_ptr;
typedef __attribute__((address_space(3))) void* lds_ptr;

__device__ __forceinline__ unsigned short f2bf(float f) {
  union { unsigned int i; float f; } v; v.f = f;
  unsigned int r = (v.i + 0x7FFF + ((v.i >> 16) & 1)) >> 16;
  return (unsigned short)r;
}
__device__ __forceinline__ void gld_lds16(const void* g, void* l) {
  __builtin_amdgcn_global_load_lds((gas_ptr)g, (lds_ptr)l, 16, 0, 0);
}

template<int NW> struct WVecT;
template<> struct WVecT<4> { using T = uint4v; };
template<> struct WVecT<2> { using T = uint2v; };

// word (2 bf16) -> 2 floats
template<int NW, typename WV>
__device__ __forceinline__ void w2f(WV w, float* f) {
  #pragma unroll
  for (int i = 0; i < NW; ++i) {
    union { unsigned int u; float x; } lo, hi;
    lo.u = w[i] << 16; hi.u = w[i] & 0xffff0000u;
    f[2 * i] = lo.x; f[2 * i + 1] = hi.x;
  }
}

// DPP butterfly add: full 16-lane sum in 4 VALU ops (rows align with 16-lane groups)
template<int CTRL>
__device__ __forceinline__ float dppadd(float v) {
  int s = __builtin_amdgcn_update_dpp(0, __float_as_int(v), CTRL, 0xf, 0xf, true);
  return v + __int_as_float(s);
}
__device__ __forceinline__ float red16(float v) {
  v = dppadd<0xB1>(v);    // quad_perm [1,0,3,2]  : xor1
  v = dppadd<0x4E>(v);    // quad_perm [2,3,0,1]  : xor2
  v = dppadd<0x140>(v);   // row_mirror           : quad q <-> 3-q
  v = dppadd<0x141>(v);   // row_half_mirror      : quad pairs
  return v;
}

// ---------------- prep: x->bf16, LDS-tiled weight transposes, bias concat ----------------
__global__ __launch_bounds__(256) void prep(
    const float* __restrict__ x,
    const float* __restrict__ Wl1, const float* __restrict__ Wr1,
    const float* __restrict__ Wl2, const float* __restrict__ Wr2,
    const float* __restrict__ Wfc,
    const float* __restrict__ bl1, const float* __restrict__ br1,
    const float* __restrict__ bl2, const float* __restrict__ br2,
    ushort* __restrict__ xb, ushort* __restrict__ wt_all,
    ushort* __restrict__ wtfc, float* __restrict__ bias_all) {
  __shared__ float tl[32][33];
  int b = blockIdx.x;
  const int tid = threadIdx.x;
  if (b < 1250) {                       // x conversion: 320000 float4 groups
    int i = b * 256 + tid;
    if (i < 320000) {
      float4 f = reinterpret_cast<const float4*>(x)[i];
      ushort4v o; o[0] = f2bf(f.x); o[1] = f2bf(f.y); o[2] = f2bf(f.z); o[3] = f2bf(f.w);
      reinterpret_cast<ushort4v*>(xb)[i] = o;
    }
    return;
  }
  b -= 1250;
  if (b < 288) {                        // weight transpose, 32x32 tiles
    const float* W; ushort* dst; int N, nOff, ldK; int t = b;
    if (t < 64)       { W = Wl1; dst = wt_all; N = 512; nOff = 0;    ldK = 128; }
    else if (t < 128) { W = Wr1; dst = wt_all; N = 512; nOff = 512;  ldK = 128; t -= 64; }
    else if (t < 160) { W = Wl2; dst = wt_all; N = 256; nOff = 1024; ldK = 128; t -= 128; }
    else if (t < 192) { W = Wr2; dst = wt_all; N = 256; nOff = 1280; ldK = 128; t -= 160; }
    else              { W = Wfc; dst = wtfc;   N = 128; nOff = 0;    ldK = 768; t -= 192; }
    const int ntn = N / 32;
    const int n0 = (t % ntn) * 32, k0 = (t / ntn) * 32;
    const int tx = tid & 31, ty = tid >> 5;   // 32 x 8
    #pragma unroll
    for (int j = 0; j < 4; ++j)
      tl[ty + j * 8][tx] = W[(size_t)(k0 + ty + j * 8) * N + n0 + tx];
    __syncthreads();
    #pragma unroll
    for (int j = 0; j < 4; ++j)
      dst[(size_t)(nOff + n0 + ty + j * 8) * ldK + k0 + tx] = f2bf(tl[tx][ty + j * 8]);
    return;
  }
  // bias concat (one block)
  for (int i = tid; i < 1536; i += 256) {
    float v = i < 512 ? bl1[i] : i < 1024 ? br1[i - 512]
            : i < 1280 ? bl2[i - 1024] : br2[i - 1280];
    bias_all[i] = v;
  }
}

// ---------------- MFMA GEMM: out[M,N] = A[M,K] @ Bt[N,K]^T (+bias) ----------------
// 64x64 tile, 4 waves, global_load_lds(16B) staging, double-buffered LDS.
template<bool OUT_BF16, int K>
__global__ __launch_bounds__(256) void gemm_mfma(
    const ushort* __restrict__ A,   // [M][K] bf16
    const ushort* __restrict__ Bt,  // [N][K] bf16 (B transposed)
    const float* __restrict__ bias, // [N] or nullptr
    void* __restrict__ outv, int M, int N, int ldOut) {
  __shared__ ushort As[2][64 * 32];
  __shared__ ushort Bs[2][64 * 32];
  const int tid  = threadIdx.x;
  const int wave = tid >> 6;
  const int lane = tid & 63;
  const int row0 = blockIdx.y * 64;
  const int col0 = blockIdx.x * 64;
  const int srow = tid >> 2;
  const int schunk = tid & 3;
  int ar = row0 + srow; if (ar >= M) ar = M - 1;   // clamp; stores guarded
  const ushort* aSrc = A  + (size_t)ar * K + schunk * 8;
  const ushort* bSrc = Bt + (size_t)(col0 + srow) * K + schunk * 8;
  const int ldsOff = tid * 8;   // 16 B per thread
  const int fr = lane & 15;
  const int kc = lane >> 4;

  f32x4 c[4];
  #pragma unroll
  for (int f = 0; f < 4; ++f) { c[f][0] = 0.f; c[f][1] = 0.f; c[f][2] = 0.f; c[f][3] = 0.f; }

  constexpr int NK = K / 32;
  gld_lds16(aSrc, &As[0][ldsOff]);
  gld_lds16(bSrc, &Bs[0][ldsOff]);
  #pragma unroll
  for (int kk = 0; kk < NK; ++kk) {
    const int cur = kk & 1;
    __syncthreads();
    if (kk + 1 < NK) {
      gld_lds16(aSrc + (kk + 1) * 32, &As[cur ^ 1][ldsOff]);
      gld_lds16(bSrc + (kk + 1) * 32, &Bs[cur ^ 1][ldsOff]);
    }
    short8 a = *reinterpret_cast<const short8*>(&As[cur][(wave * 16 + fr) * 32 + kc * 8]);
    #pragma unroll
    for (int f = 0; f < 4; ++f) {
      short8 b = *reinterpret_cast<const short8*>(&Bs[cur][(f * 16 + fr) * 32 + kc * 8]);
      c[f] = __builtin_amdgcn_mfma_f32_16x16x32_bf16(a, b, c[f], 0, 0, 0);
    }
  }
  const int orow = row0 + wave * 16 + (lane >> 4) * 4;
  #pragma unroll
  for (int f = 0; f < 4; ++f) {
    const int col = col0 + f * 16 + fr;
    const float bv = bias ? bias[col] : 0.f;
    #pragma unroll
    for (int q = 0; q < 4; ++q) {
      const int r = orow + q;
      if (r < M) {
        float v = c[f][q] + bv;
        if (OUT_BF16) ((ushort*)outv)[(size_t)r * ldOut + col] = f2bf(v);
        else          ((float*) outv)[(size_t)r * ldOut + col] = v;
      }
    }
  }
}

// ---------------- CSR build ----------------
__global__ __launch_bounds__(256) void hist2(const int* __restrict__ dl,
    const int* __restrict__ dg, int* __restrict__ c1, int* __restrict__ c2) {
  int i = blockIdx.x * blockDim.x + threadIdx.x;
  if (i < E_LOCAL) atomicAdd(&c1[dl[i]], 1);
  else if (i < E_LOCAL + E_GLOBAL) atomicAdd(&c2[dg[i - E_LOCAL]], 1);
}

__global__ __launch_bounds__(256) void scan2(int* __restrict__ cnt1, int* __restrict__ cur1,
    int* __restrict__ cnt2, int* __restrict__ cur2) {
  int* cnt = blockIdx.x == 0 ? cnt1 : cnt2;
  int* cur = blockIdx.x == 0 ? cur1 : cur2;
  __shared__ int sums[256];
  const int t = threadIdx.x;
  const int CH = CNT_LEN / 256;   // 40
  int s = 0;
  for (int j = 0; j < CH; ++j) s += cnt[t * CH + j];
  sums[t] = s;
  __syncthreads();
  for (int o = 1; o < 256; o <<= 1) {
    int v = (t >= o) ? sums[t - o] : 0;
    __syncthreads();
    sums[t] += v;
    __syncthreads();
  }
  int prefix = (t == 0) ? 0 : sums[t - 1];
  for (int j = 0; j < CH; ++j) {
    int idx = t * CH + j;
    int c = cnt[idx];
    cnt[idx] = prefix;
    cur[idx] = prefix;
    prefix += c;
  }
}

__global__ __launch_bounds__(256) void scatter2(
    const int* __restrict__ sl, const int* __restrict__ dl,
    const int* __restrict__ sg, const int* __restrict__ dg,
    int* __restrict__ cur1, int* __restrict__ cur2,
    int* __restrict__ csr1, int* __restrict__ csr2) {
  int i = blockIdx.x * blockDim.x + threadIdx.x;
  if (i < E_LOCAL) {
    int pos = atomicAdd(&cur1[dl[i]], 1);
    csr1[pos] = sl[i];
  } else if (i < E_LOCAL + E_GLOBAL) {
    int j = i - E_LOCAL;
    int pos = atomicAdd(&cur2[dg[j]], 1);
    csr2[pos] = sg[j];
  }
}

// ---------------- Node-stationary aggregation ----------------
// Ping-pong software pipeline: gathers for batch b+1 and csr indices for
// batch b+2 issue BEFORE computing batch b. DPP butterfly reduce.
template<int H, int U>
__global__ __launch_bounds__(256) void aggregate(
    const ushort* __restrict__ xl, const ushort* __restrict__ xr,
    const float* __restrict__ att, const int* __restrict__ csr,
    const int* __restrict__ off, const float* __restrict__ bias,
    int inLd, ushort* __restrict__ outp, int outLd) {
  constexpr int TC = H * 128;      // channels this layer
  constexpr int PER = TC / 64;     // elems per lane
  constexpr int NW = PER / 2;      // 32-bit words per lane
  constexpr int GRP = 64 / H;      // lanes per head
  using WVec = typename WVecT<NW>::T;
  const int lane = threadIdx.x & 63;
  const int node = (int)(((long)blockIdx.x * blockDim.x + threadIdx.x) >> 6);
  if (node >= N_NODES) return;
  const int base = lane * PER;

  float attv[PER], xri[PER], acc[PER];
  #pragma unroll
  for (int p = 0; p < PER; ++p) attv[p] = att[base + p];
  {
    WVec r = *reinterpret_cast<const WVec*>(&xr[(size_t)node * inLd + base]);
    w2f<NW>(r, xri);
  }

  // self-loop message
  float den;
  {
    WVec r = *reinterpret_cast<const WVec*>(&xl[(size_t)node * inLd + base]);
    float xs[PER]; w2f<NW>(r, xs);
    float part = 0.f;
    #pragma unroll
    for (int p = 0; p < PER; ++p) {
      float t = xs[p] + xri[p];
      t = fmaxf(t, 0.2f * t);
      part = fmaf(t, attv[p], part);
    }
    part = red16(part);
    if (GRP == 32) part += __shfl_xor(part, 16, 64);
    den = __expf(part);
    #pragma unroll
    for (int p = 0; p < PER; ++p) acc[p] = den * xs[p];
  }

  const int e0 = off[node];
  const int e1 = off[node + 1];
  const int nfull = (e1 - e0) / U;
  WVec rA[U], rB[U];
  int iC[U], iN[U];
  if (nfull > 0) {
    #pragma unroll
    for (int m = 0; m < U; ++m) iC[m] = csr[e0 + m];
    #pragma unroll
    for (int m = 0; m < U; ++m)
      rA[m] = *reinterpret_cast<const WVec*>(&xl[(size_t)iC[m] * inLd + base]);
    if (nfull > 1) {
      #pragma unroll
      for (int m = 0; m < U; ++m) iC[m] = csr[e0 + U + m];
    }
  }
  for (int b = 0; b < nfull; ++b) {
    if (b + 2 < nfull) {
      #pragma unroll
      for (int m = 0; m < U; ++m) iN[m] = csr[e0 + (b + 2) * U + m];
    }
    if (b + 1 < nfull) {
      #pragma unroll
      for (int m = 0; m < U; ++m)
        rB[m] = *reinterpret_cast<const WVec*>(&xl[(size_t)iC[m] * inLd + base]);
    }
    // compute current batch
    float pp[U];
    #pragma unroll
    for (int m = 0; m < U; ++m) {
      float xs[PER]; w2f<NW>(rA[m], xs);
      float d = 0.f;
      #pragma unroll
      for (int p = 0; p < PER; ++p) {
        float t = xs[p] + xri[p];
        t = fmaxf(t, 0.2f * t);
        d = fmaf(t, attv[p], d);
      }
      pp[m] = d;
    }
    #pragma unroll
    for (int m = 0; m < U; ++m) pp[m] = red16(pp[m]);
    if (GRP == 32) {
      #pragma unroll
      for (int m = 0; m < U; ++m) pp[m] += __shfl_xor(pp[m], 16, 64);
    }
    #pragma unroll
    for (int m = 0; m < U; ++m) {
      float w = __expf(pp[m]);
      den += w;
      float xs[PER]; w2f<NW>(rA[m], xs);
      #pragma unroll
      for (int p = 0; p < PER; ++p) acc[p] = fmaf(w, xs[p], acc[p]);
    }
    #pragma unroll
    for (int m = 0; m < U; ++m) { rA[m] = rB[m]; iC[m] = iN[m]; }
  }
  // remainder
  for (int e = e0 + nfull * U; e < e1; ++e) {
    int s = csr[e];
    WVec r = *reinterpret_cast<const WVec*>(&xl[(size_t)s * inLd + base]);
    float xs[PER]; w2f<NW>(r, xs);
    float d = 0.f;
    #pragma unroll
    for (int p = 0; p < PER; ++p) {
      float t = xs[p] + xri[p];
      t = fmaxf(t, 0.2f * t);
      d = fmaf(t, attv[p], d);
    }
    d = red16(d);
    if (GRP == 32) d += __shfl_xor(d, 16, 64);
    float w = __expf(d);
    den += w;
    #pragma unroll
    for (int p = 0; p < PER; ++p) acc[p] = fmaf(w, xs[p], acc[p]);
  }

  const float inv = 1.f / den;
  #pragma unroll
  for (int v = 0; v < PER / 4; ++v) {
    ushort4v o;
    #pragma unroll
    for (int q = 0; q < 4; ++q)
      o[q] = f2bf(fmaf(acc[v * 4 + q], inv, bias[base + v * 4 + q]));
    *reinterpret_cast<ushort4v*>(&outp[(size_t)node * outLd + base + v * 4]) = o;
  }
}

extern "C" void kernel_launch(void* const* d_in, const int* in_sizes, int n_in,
                              void* d_out, int out_size, void* d_ws, size_t ws_size,
                              hipStream_t stream) {
  const float* x    = (const float*)d_in[0];
  const int*   ei   = (const int*)d_in[1];   // [2, E_LOCAL]
  const int*   gei  = (const int*)d_in[2];   // [2, E_GLOBAL]
  const float* Wl1  = (const float*)d_in[3];
  const float* bl1  = (const float*)d_in[4];
  const float* Wr1  = (const float*)d_in[5];
  const float* br1  = (const float*)d_in[6];
  const float* att1 = (const float*)d_in[7];
  const float* b1   = (const float*)d_in[8];
  const float* Wl2  = (const float*)d_in[9];
  const float* bl2  = (const float*)d_in[10];
  const float* Wr2  = (const float*)d_in[11];
  const float* br2  = (const float*)d_in[12];
  const float* att2 = (const float*)d_in[13];
  const float* b2   = (const float*)d_in[14];
  const float* Wfc  = (const float*)d_in[15];
  const float* bfc  = (const float*)d_in[16];
  float* out = (float*)d_out;

  char* w = (char*)d_ws;
  ushort* xb     = (ushort*)w; w += (size_t)N_NODES * 128 * 2;
  ushort* feat   = (ushort*)w; w += (size_t)N_NODES * 1536 * 2;  // xl1|xr1|xl2|xr2
  ushort* hb     = (ushort*)w; w += (size_t)N_NODES * 768 * 2;   // concat [N][768]
  ushort* wt_all = (ushort*)w; w += (size_t)1536 * 128 * 2;
  ushort* wtfc   = (ushort*)w; w += (size_t)128 * 768 * 2;
  float* bias_all = (float*)w; w += 1536 * 4;
  int* off1 = (int*)w;
  int* off2 = off1 + CNT_LEN;
  int* cur1 = off2 + CNT_LEN;
  int* cur2 = cur1 + CNT_LEN;
  int* csr1 = cur2 + CNT_LEN;   // E_LOCAL
  int* csr2 = csr1 + E_LOCAL;   // E_GLOBAL

  hipMemsetAsync(off1, 0, 2 * CNT_LEN * sizeof(int), stream);

  const int N = N_NODES;
  // conversions + transposes + bias concat
  prep<<<1539, 256, 0, stream>>>(x, Wl1, Wr1, Wl2, Wr2, Wfc,
                                 bl1, br1, bl2, br2,
                                 xb, wt_all, wtfc, bias_all);

  // CSR build (by destination)
  hist2<<<(E_LOCAL + E_GLOBAL + 255) / 256, 256, 0, stream>>>(
      ei + E_LOCAL, gei + E_GLOBAL, off1, off2);
  scan2<<<2, 256, 0, stream>>>(off1, cur1, off2, cur2);
  scatter2<<<(E_LOCAL + E_GLOBAL + 255) / 256, 256, 0, stream>>>(
      ei, ei + E_LOCAL, gei, gei + E_GLOBAL, cur1, cur2, csr1, csr2);

  // Fused input transform: [10000x128] @ [128x1536] -> feat
  gemm_mfma<true, 128><<<dim3(24, 157), 256, 0, stream>>>(
      xb, wt_all, bias_all, feat, N, 1536, 1536);

  // Node-stationary aggregation -> concat buffer hb [N][768]
  aggregate<4, 3><<<(N * 64 + 255) / 256, 256, 0, stream>>>(
      feat, feat + 512, att1, csr1, off1, b1, 1536, hb, 768);
  aggregate<2, 4><<<(N * 64 + 255) / 256, 256, 0, stream>>>(
      feat + 1024, feat + 1280, att2, csr2, off2, b2, 1536, hb + 512, 768);

  // Final FC: one MFMA GEMM over concat, f32 out
  gemm_mfma<false, 768><<<dim3(2, 157), 256, 0, stream>>>(hb, wtfc, bfc, out, N, 128, 128);
}

// Round 12
// 246.895 us; speedup vs baseline: 27.9022x; 1.3988x over previous
//
#include <hip/hip_runtime.h>

#define N_NODES 10000
#define E_LOCAL 320000
#define E_GLOBAL 640000
#define CNT_LEN 10240   // padded node range (160 buckets x 64)
#define NB 160          // buckets per layer (64 node-ids each)
#define BCAP1 3072      // local bucket capacity  (mean 1280, +~50 sigma)
#define BCAP2 5632      // global bucket capacity (mean 2560, +~60 sigma)
#define CHUNK 2048      // edges per bucketize workgroup
#define NWG_L 157       // ceil(E_LOCAL/CHUNK)
#define NWG_G 313       // ceil(E_GLOBAL/CHUNK)

typedef __attribute__((ext_vector_type(8))) short short8;
typedef __attribute__((ext_vector_type(4))) float f32x4;
typedef __attribute__((ext_vector_type(4))) unsigned short ushort4v;
typedef __attribute__((ext_vector_type(2))) unsigned int uint2v;
typedef __attribute__((ext_vector_type(4))) unsigned int uint4v;

typedef __attribute__((address_space(1))) const void* gas_ptr;
typedef __attribute__((address_space(3))) void* lds_ptr;

__device__ __forceinline__ unsigned short f2bf(float f) {
  union { unsigned int i; float f; } v; v.f = f;
  unsigned int r = (v.i + 0x7FFF + ((v.i >> 16) & 1)) >> 16;
  return (unsigned short)r;
}
__device__ __forceinline__ void gld_lds16(const void* g, void* l) {
  __builtin_amdgcn_global_load_lds((gas_ptr)g, (lds_ptr)l, 16, 0, 0);
}

template<int NW> struct WVecT;
template<> struct WVecT<4> { using T = uint4v; };
template<> struct WVecT<2> { using T = uint2v; };

// word (2 bf16) -> 2 floats
template<int NW, typename WV>
__device__ __forceinline__ void w2f(WV w, float* f) {
  #pragma unroll
  for (int i = 0; i < NW; ++i) {
    union { unsigned int u; float x; } lo, hi;
    lo.u = w[i] << 16; hi.u = w[i] & 0xffff0000u;
    f[2 * i] = lo.x; f[2 * i + 1] = hi.x;
  }
}

// DPP butterfly add: full 16-lane sum in 4 VALU ops
template<int CTRL>
__device__ __forceinline__ float dppadd(float v) {
  int s = __builtin_amdgcn_update_dpp(0, __float_as_int(v), CTRL, 0xf, 0xf, true);
  return v + __int_as_float(s);
}
__device__ __forceinline__ float red16(float v) {
  v = dppadd<0xB1>(v);    // quad_perm [1,0,3,2]  : xor1
  v = dppadd<0x4E>(v);    // quad_perm [2,3,0,1]  : xor2
  v = dppadd<0x140>(v);   // row_mirror
  v = dppadd<0x141>(v);   // row_half_mirror
  return v;
}

// ---------------- prep: x->bf16, weight transposes, bias concat, bcur zero ----------------
__global__ __launch_bounds__(256) void prep(
    const float* __restrict__ x,
    const float* __restrict__ Wl1, const float* __restrict__ Wr1,
    const float* __restrict__ Wl2, const float* __restrict__ Wr2,
    const float* __restrict__ Wfc,
    const float* __restrict__ bl1, const float* __restrict__ br1,
    const float* __restrict__ bl2, const float* __restrict__ br2,
    ushort* __restrict__ xb, ushort* __restrict__ wt_all,
    ushort* __restrict__ wtfc, float* __restrict__ bias_all,
    int* __restrict__ bcur) {
  __shared__ float tl[32][33];
  int b = blockIdx.x;
  const int tid = threadIdx.x;
  if (b < 1250) {                       // x conversion: 320000 float4 groups
    int i = b * 256 + tid;
    if (i < 320000) {
      float4 f = reinterpret_cast<const float4*>(x)[i];
      ushort4v o; o[0] = f2bf(f.x); o[1] = f2bf(f.y); o[2] = f2bf(f.z); o[3] = f2bf(f.w);
      reinterpret_cast<ushort4v*>(xb)[i] = o;
    }
    return;
  }
  b -= 1250;
  if (b < 288) {                        // weight transpose, 32x32 tiles
    const float* W; ushort* dst; int N, nOff, ldK; int t = b;
    if (t < 64)       { W = Wl1; dst = wt_all; N = 512; nOff = 0;    ldK = 128; }
    else if (t < 128) { W = Wr1; dst = wt_all; N = 512; nOff = 512;  ldK = 128; t -= 64; }
    else if (t < 160) { W = Wl2; dst = wt_all; N = 256; nOff = 1024; ldK = 128; t -= 128; }
    else if (t < 192) { W = Wr2; dst = wt_all; N = 256; nOff = 1280; ldK = 128; t -= 160; }
    else              { W = Wfc; dst = wtfc;   N = 128; nOff = 0;    ldK = 768; t -= 192; }
    const int ntn = N / 32;
    const int n0 = (t % ntn) * 32, k0 = (t / ntn) * 32;
    const int tx = tid & 31, ty = tid >> 5;   // 32 x 8
    #pragma unroll
    for (int j = 0; j < 4; ++j)
      tl[ty + j * 8][tx] = W[(size_t)(k0 + ty + j * 8) * N + n0 + tx];
    __syncthreads();
    #pragma unroll
    for (int j = 0; j < 4; ++j)
      dst[(size_t)(nOff + n0 + ty + j * 8) * ldK + k0 + tx] = f2bf(tl[tx][ty + j * 8]);
    return;
  }
  // bias concat + bcur zero (one block)
  for (int i = tid; i < 1536; i += 256) {
    float v = i < 512 ? bl1[i] : i < 1024 ? br1[i - 512]
            : i < 1280 ? bl2[i - 1024] : br2[i - 1280];
    bias_all[i] = v;
  }
  for (int i = tid; i < 2 * NB; i += 256) bcur[i] = 0;
}

// ---------------- MFMA GEMM: out[M,N] = A[M,K] @ Bt[N,K]^T (+bias) ----------------
template<bool OUT_BF16, int K>
__global__ __launch_bounds__(256) void gemm_mfma(
    const ushort* __restrict__ A,   // [M][K] bf16
    const ushort* __restrict__ Bt,  // [N][K] bf16 (B transposed)
    const float* __restrict__ bias, // [N] or nullptr
    void* __restrict__ outv, int M, int N, int ldOut) {
  __shared__ ushort As[2][64 * 32];
  __shared__ ushort Bs[2][64 * 32];
  const int tid  = threadIdx.x;
  const int wave = tid >> 6;
  const int lane = tid & 63;
  const int row0 = blockIdx.y * 64;
  const int col0 = blockIdx.x * 64;
  const int srow = tid >> 2;
  const int schunk = tid & 3;
  int ar = row0 + srow; if (ar >= M) ar = M - 1;   // clamp; stores guarded
  const ushort* aSrc = A  + (size_t)ar * K + schunk * 8;
  const ushort* bSrc = Bt + (size_t)(col0 + srow) * K + schunk * 8;
  const int ldsOff = tid * 8;   // 16 B per thread
  const int fr = lane & 15;
  const int kc = lane >> 4;

  f32x4 c[4];
  #pragma unroll
  for (int f = 0; f < 4; ++f) { c[f][0] = 0.f; c[f][1] = 0.f; c[f][2] = 0.f; c[f][3] = 0.f; }

  constexpr int NK = K / 32;
  gld_lds16(aSrc, &As[0][ldsOff]);
  gld_lds16(bSrc, &Bs[0][ldsOff]);
  #pragma unroll
  for (int kk = 0; kk < NK; ++kk) {
    const int cur = kk & 1;
    __syncthreads();
    if (kk + 1 < NK) {
      gld_lds16(aSrc + (kk + 1) * 32, &As[cur ^ 1][ldsOff]);
      gld_lds16(bSrc + (kk + 1) * 32, &Bs[cur ^ 1][ldsOff]);
    }
    short8 a = *reinterpret_cast<const short8*>(&As[cur][(wave * 16 + fr) * 32 + kc * 8]);
    #pragma unroll
    for (int f = 0; f < 4; ++f) {
      short8 b = *reinterpret_cast<const short8*>(&Bs[cur][(f * 16 + fr) * 32 + kc * 8]);
      c[f] = __builtin_amdgcn_mfma_f32_16x16x32_bf16(a, b, c[f], 0, 0, 0);
    }
  }
  const int orow = row0 + wave * 16 + (lane >> 4) * 4;
  #pragma unroll
  for (int f = 0; f < 4; ++f) {
    const int col = col0 + f * 16 + fr;
    const float bv = bias ? bias[col] : 0.f;
    #pragma unroll
    for (int q = 0; q < 4; ++q) {
      const int r = orow + q;
      if (r < M) {
        float v = c[f][q] + bv;
        if (OUT_BF16) ((ushort*)outv)[(size_t)r * ldOut + col] = f2bf(v);
        else          ((float*) outv)[(size_t)r * ldOut + col] = v;
      }
    }
  }
}

// ---------------- bucketed CSR build ----------------
// Pass 1: bucketize edges. LDS histogram -> one global reserve per (wg,bucket)
// -> append (src,dst) pairs into the bucket's contiguous slice.
__global__ __launch_bounds__(256) void bucketize(
    const int* __restrict__ sl, const int* __restrict__ dl,
    const int* __restrict__ sg, const int* __restrict__ dg,
    int* __restrict__ bcur, uint2* __restrict__ bb1, uint2* __restrict__ bb2) {
  __shared__ int h[NB];
  __shared__ int cur[NB];
  const int tid = threadIdx.x;
  int wg = blockIdx.x;
  const int* S; const int* D; int E0, Etot; uint2* BB; int* BC; int cap;
  if (wg < NWG_L) { S = sl; D = dl; E0 = wg * CHUNK; Etot = E_LOCAL;  BB = bb1; BC = bcur;      cap = BCAP1; }
  else { wg -= NWG_L; S = sg; D = dg; E0 = wg * CHUNK; Etot = E_GLOBAL; BB = bb2; BC = bcur + NB; cap = BCAP2; }
  for (int i = tid; i < NB; i += 256) h[i] = 0;
  __syncthreads();
  int myd[8], mys[8];
  #pragma unroll
  for (int k = 0; k < 8; ++k) {
    int e = E0 + k * 256 + tid;
    if (e < Etot) { myd[k] = D[e]; mys[k] = S[e]; atomicAdd(&h[myd[k] >> 6], 1); }
    else myd[k] = -1;
  }
  __syncthreads();
  for (int b = tid; b < NB; b += 256)
    cur[b] = h[b] ? atomicAdd(&BC[b], h[b]) : 0;   // global base for this wg's run
  __syncthreads();
  #pragma unroll
  for (int k = 0; k < 8; ++k) {
    if (myd[k] >= 0) {
      int b = myd[k] >> 6;
      int pos = atomicAdd(&cur[b], 1);             // LDS cursor holds global pos
      if (pos < cap) BB[(size_t)b * cap + pos] = make_uint2((unsigned)mys[k], (unsigned)myd[k]);
    }
  }
}

// Pass 1.5: exclusive scan of bucket sizes (per layer) -> csr bases. One block, 320 threads.
__global__ __launch_bounds__(320) void scanb(const int* __restrict__ bcur,
                                             int* __restrict__ base) {
  __shared__ int v[2 * NB];
  __shared__ int sz[2 * NB];
  const int t = threadIdx.x;
  const int ls = (t < NB) ? 0 : NB;
  int s = min(bcur[t], (t < NB) ? BCAP1 : BCAP2);
  sz[t] = s; v[t] = s;
  __syncthreads();
  for (int o = 1; o < NB; o <<= 1) {
    int add = (t - o >= ls) ? v[t - o] : 0;
    __syncthreads();
    v[t] += add;
    __syncthreads();
  }
  base[t] = v[t] - sz[t];   // exclusive
}

// Pass 2: per-bucket node-level counting sort -> csr + off. No global atomics.
__global__ __launch_bounds__(256) void csrbuild(
    const int* __restrict__ bcur, const int* __restrict__ base,
    const uint2* __restrict__ bb1, const uint2* __restrict__ bb2,
    int* __restrict__ csr1, int* __restrict__ csr2,
    int* __restrict__ off1, int* __restrict__ off2) {
  __shared__ int nh[64];
  __shared__ int ncur[64];
  const int tid = threadIdx.x;
  const int b = blockIdx.x;
  const uint2* BB; int* csr; int* off; int cap; int bi;
  if (b < NB) { BB = bb1; csr = csr1; off = off1; cap = BCAP1; bi = b; }
  else        { BB = bb2; csr = csr2; off = off2; cap = BCAP2; bi = b - NB; }
  const int n = min(bcur[b], cap);
  const uint2* P = BB + (size_t)bi * cap;
  if (tid < 64) nh[tid] = 0;
  __syncthreads();
  for (int i = tid; i < n; i += 256) atomicAdd(&nh[P[i].y & 63], 1);
  __syncthreads();
  if (tid == 0) {
    int s = base[b];
    #pragma unroll 4
    for (int j = 0; j < 64; ++j) { int c = nh[j]; nh[j] = s; s += c; }
  }
  __syncthreads();
  if (tid < 64) { off[bi * 64 + tid] = nh[tid]; ncur[tid] = nh[tid]; }
  __syncthreads();
  for (int i = tid; i < n; i += 256) {
    uint2 p = P[i];
    int pos = atomicAdd(&ncur[p.y & 63], 1);
    csr[pos] = (int)p.x;
  }
}

// ---------------- Node-stationary aggregation ----------------
// Ping-pong software pipeline + DPP butterfly reduce.
template<int H, int U>
__global__ __launch_bounds__(256) void aggregate(
    const ushort* __restrict__ xl, const ushort* __restrict__ xr,
    const float* __restrict__ att, const int* __restrict__ csr,
    const int* __restrict__ off, const float* __restrict__ bias,
    int inLd, ushort* __restrict__ outp, int outLd) {
  constexpr int TC = H * 128;
  constexpr int PER = TC / 64;
  constexpr int NW = PER / 2;
  constexpr int GRP = 64 / H;
  using WVec = typename WVecT<NW>::T;
  const int lane = threadIdx.x & 63;
  const int node = (int)(((long)blockIdx.x * blockDim.x + threadIdx.x) >> 6);
  if (node >= N_NODES) return;
  const int base = lane * PER;

  float attv[PER], xri[PER], acc[PER];
  #pragma unroll
  for (int p = 0; p < PER; ++p) attv[p] = att[base + p];
  {
    WVec r = *reinterpret_cast<const WVec*>(&xr[(size_t)node * inLd + base]);
    w2f<NW>(r, xri);
  }

  float den;
  {
    WVec r = *reinterpret_cast<const WVec*>(&xl[(size_t)node * inLd + base]);
    float xs[PER]; w2f<NW>(r, xs);
    float part = 0.f;
    #pragma unroll
    for (int p = 0; p < PER; ++p) {
      float t = xs[p] + xri[p];
      t = fmaxf(t, 0.2f * t);
      part = fmaf(t, attv[p], part);
    }
    part = red16(part);
    if (GRP == 32) part += __shfl_xor(part, 16, 64);
    den = __expf(part);
    #pragma unroll
    for (int p = 0; p < PER; ++p) acc[p] = den * xs[p];
  }

  const int e0 = off[node];
  const int e1 = off[node + 1];
  const int nfull = (e1 - e0) / U;
  WVec rA[U], rB[U];
  int iC[U], iN[U];
  if (nfull > 0) {
    #pragma unroll
    for (int m = 0; m < U; ++m) iC[m] = csr[e0 + m];
    #pragma unroll
    for (int m = 0; m < U; ++m)
      rA[m] = *reinterpret_cast<const WVec*>(&xl[(size_t)iC[m] * inLd + base]);
    if (nfull > 1) {
      #pragma unroll
      for (int m = 0; m < U; ++m) iC[m] = csr[e0 + U + m];
    }
  }
  for (int b = 0; b < nfull; ++b) {
    if (b + 2 < nfull) {
      #pragma unroll
      for (int m = 0; m < U; ++m) iN[m] = csr[e0 + (b + 2) * U + m];
    }
    if (b + 1 < nfull) {
      #pragma unroll
      for (int m = 0; m < U; ++m)
        rB[m] = *reinterpret_cast<const WVec*>(&xl[(size_t)iC[m] * inLd + base]);
    }
    float pp[U];
    #pragma unroll
    for (int m = 0; m < U; ++m) {
      float xs[PER]; w2f<NW>(rA[m], xs);
      float d = 0.f;
      #pragma unroll
      for (int p = 0; p < PER; ++p) {
        float t = xs[p] + xri[p];
        t = fmaxf(t, 0.2f * t);
        d = fmaf(t, attv[p], d);
      }
      pp[m] = d;
    }
    #pragma unroll
    for (int m = 0; m < U; ++m) pp[m] = red16(pp[m]);
    if (GRP == 32) {
      #pragma unroll
      for (int m = 0; m < U; ++m) pp[m] += __shfl_xor(pp[m], 16, 64);
    }
    #pragma unroll
    for (int m = 0; m < U; ++m) {
      float w = __expf(pp[m]);
      den += w;
      float xs[PER]; w2f<NW>(rA[m], xs);
      #pragma unroll
      for (int p = 0; p < PER; ++p) acc[p] = fmaf(w, xs[p], acc[p]);
    }
    #pragma unroll
    for (int m = 0; m < U; ++m) { rA[m] = rB[m]; iC[m] = iN[m]; }
  }
  for (int e = e0 + nfull * U; e < e1; ++e) {
    int s = csr[e];
    WVec r = *reinterpret_cast<const WVec*>(&xl[(size_t)s * inLd + base]);
    float xs[PER]; w2f<NW>(r, xs);
    float d = 0.f;
    #pragma unroll
    for (int p = 0; p < PER; ++p) {
      float t = xs[p] + xri[p];
      t = fmaxf(t, 0.2f * t);
      d = fmaf(t, attv[p], d);
    }
    d = red16(d);
    if (GRP == 32) d += __shfl_xor(d, 16, 64);
    float w = __expf(d);
    den += w;
    #pragma unroll
    for (int p = 0; p < PER; ++p) acc[p] = fmaf(w, xs[p], acc[p]);
  }

  const float inv = 1.f / den;
  #pragma unroll
  for (int v = 0; v < PER / 4; ++v) {
    ushort4v o;
    #pragma unroll
    for (int q = 0; q < 4; ++q)
      o[q] = f2bf(fmaf(acc[v * 4 + q], inv, bias[base + v * 4 + q]));
    *reinterpret_cast<ushort4v*>(&outp[(size_t)node * outLd + base + v * 4]) = o;
  }
}

extern "C" void kernel_launch(void* const* d_in, const int* in_sizes, int n_in,
                              void* d_out, int out_size, void* d_ws, size_t ws_size,
                              hipStream_t stream) {
  const float* x    = (const float*)d_in[0];
  const int*   ei   = (const int*)d_in[1];   // [2, E_LOCAL]
  const int*   gei  = (const int*)d_in[2];   // [2, E_GLOBAL]
  const float* Wl1  = (const float*)d_in[3];
  const float* bl1  = (const float*)d_in[4];
  const float* Wr1  = (const float*)d_in[5];
  const float* br1  = (const float*)d_in[6];
  const float* att1 = (const float*)d_in[7];
  const float* b1   = (const float*)d_in[8];
  const float* Wl2  = (const float*)d_in[9];
  const float* bl2  = (const float*)d_in[10];
  const float* Wr2  = (const float*)d_in[11];
  const float* br2  = (const float*)d_in[12];
  const float* att2 = (const float*)d_in[13];
  const float* b2   = (const float*)d_in[14];
  const float* Wfc  = (const float*)d_in[15];
  const float* bfc  = (const float*)d_in[16];
  float* out = (float*)d_out;

  char* w = (char*)d_ws;
  ushort* xb     = (ushort*)w; w += (size_t)N_NODES * 128 * 2;
  ushort* feat   = (ushort*)w; w += (size_t)N_NODES * 1536 * 2;  // xl1|xr1|xl2|xr2
  ushort* hb     = (ushort*)w; w += (size_t)N_NODES * 768 * 2;   // concat [N][768]
  ushort* wt_all = (ushort*)w; w += (size_t)1536 * 128 * 2;
  ushort* wtfc   = (ushort*)w; w += (size_t)128 * 768 * 2;
  float* bias_all = (float*)w; w += 1536 * 4;
  int* off1 = (int*)w;            w += (size_t)CNT_LEN * 4;
  int* off2 = (int*)w;            w += (size_t)CNT_LEN * 4;
  int* csr1 = (int*)w;            w += (size_t)E_LOCAL * 4;
  int* csr2 = (int*)w;            w += (size_t)E_GLOBAL * 4;
  int* bcur = (int*)w;            w += 2 * NB * 4;
  int* bbase = (int*)w;           w += 2 * NB * 4;
  uint2* bb1 = (uint2*)w;         w += (size_t)NB * BCAP1 * 8;
  uint2* bb2 = (uint2*)w;         w += (size_t)NB * BCAP2 * 8;

  const int N = N_NODES;
  // conversions + transposes + bias concat + bcur zero
  prep<<<1539, 256, 0, stream>>>(x, Wl1, Wr1, Wl2, Wr2, Wfc,
                                 bl1, br1, bl2, br2,
                                 xb, wt_all, wtfc, bias_all, bcur);

  // Bucketed CSR build (no per-node global atomics, coalesced appends)
  bucketize<<<NWG_L + NWG_G, 256, 0, stream>>>(
      ei, ei + E_LOCAL, gei, gei + E_GLOBAL, bcur, bb1, bb2);
  scanb<<<1, 320, 0, stream>>>(bcur, bbase);
  csrbuild<<<2 * NB, 256, 0, stream>>>(bcur, bbase, bb1, bb2,
                                       csr1, csr2, off1, off2);

  // Fused input transform: [10000x128] @ [128x1536] -> feat
  gemm_mfma<true, 128><<<dim3(24, 157), 256, 0, stream>>>(
      xb, wt_all, bias_all, feat, N, 1536, 1536);

  // Node-stationary aggregation -> concat buffer hb [N][768]
  aggregate<4, 3><<<(N * 64 + 255) / 256, 256, 0, stream>>>(
      feat, feat + 512, att1, csr1, off1, b1, 1536, hb, 768);
  aggregate<2, 4><<<(N * 64 + 255) / 256, 256, 0, stream>>>(
      feat + 1024, feat + 1280, att2, csr2, off2, b2, 1536, hb + 512, 768);

  // Final FC: one MFMA GEMM over concat, f32 out
  gemm_mfma<false, 768><<<dim3(2, 157), 256, 0, stream>>>(hb, wtfc, bfc, out, N, 128, 128);
}